// Round 2
// baseline (6461.640 us; speedup 1.0000x reference)
//
#include <hip/hip_runtime.h>
#include <cstdint>
#include <cstddef>

// ---------------- problem constants ----------------
#define V_SZ 50257
#define H_SZ 512
#define S_SZ 128
#define NBEAM 5
#define TMAXX 32
#define TOK_SOS 1
#define TOK_EOS 2
#define NEGINF (-1e9f)

// ---------------- launch shape ----------------
#define GW 128            // decode workgroups (measured faster than 256: sync/serial-bound)
#define NT 512
#define GENC 16           // encoder WGs (Whh register-resident)
#define COLS_PER_WG 393   // ceil(V/GW)

// ---------------- barrier ints (start of ws; first 8 KiB memset to 0) ----------------
#define BI_LEAF(l)  ((l)*32)        // 8 leaf counters (16 WGs each)
#define BI_ROOT     544
#define BI_REL(l)   (1024 + (l)*32) // 8 per-leaf release generations
#define BI_ECNT     1792
#define BI_EREL     1824

// ---------------- float region: fb = (float*)ws + 2048 ----------------
#define OF_GI    0            // 128*1536
#define OF_ENC   196608       // 128*512
#define OF_EW    262144       // 128*512  enc_out @ Wc_bottom
#define OF_H2    327680       // [2][5][512] ping-pong decoder hidden
#define OF_AL    332800       // [5][128] attention logits
#define OF_OTOP  333440       // [5][512] h2 @ Wc_top (flat b*512+j)
#define OF_PV    336000       // [<=256][5][5]
#define OF_PM    342400       // [<=256][5]
#define OF_PS    343680       // [<=256][5]
#define OF_SC    344960       // [8]
#define OI_BASE  344968
#define I_TOK 6400
#define I_FIN 6408
#define I_LEN 6416
#define I_PAR 6424
#define I_SEQ 6432

template <typename T>
__device__ __forceinline__ T aload(const T* p){
  return __hip_atomic_load((T*)p, __ATOMIC_RELAXED, __HIP_MEMORY_SCOPE_AGENT);
}
template <typename T>
__device__ __forceinline__ void astore(T* p, T v){
  __hip_atomic_store(p, v, __ATOMIC_RELAXED, __HIP_MEMORY_SCOPE_AGENT);
}

__device__ __forceinline__ float wredsum(float a){
#pragma unroll
  for (int m = 32; m; m >>= 1) a += __shfl_xor(a, m, 64);
  return a;
}

// fence-free device barrier over GW WGs; last-arriving WG runs tail() before release.
template <typename F>
__device__ __forceinline__ void dbar(int* bi, int wid, F&& tail){
  __shared__ int s_last;
  int mygen = 0;
  __syncthreads();
  if (threadIdx.x == 0){
    int leaf = wid >> 4;
    mygen = aload(bi + BI_REL(leaf));
    __builtin_amdgcn_s_waitcnt(0);
    int lo = __hip_atomic_fetch_add(bi + BI_LEAF(leaf), 1, __ATOMIC_RELAXED, __HIP_MEMORY_SCOPE_AGENT);
    int last = 0;
    if (lo == 15){
      astore(bi + BI_LEAF(leaf), 0);
      __builtin_amdgcn_s_waitcnt(0);     // leaf reset at L3 before root arrive
      int ro = __hip_atomic_fetch_add(bi + BI_ROOT, 1, __ATOMIC_RELAXED, __HIP_MEMORY_SCOPE_AGENT);
      if (ro == (GW/16) - 1){
        astore(bi + BI_ROOT, 0);
        last = 1;
      }
    }
    if (!last){
      while (aload(bi + BI_REL(leaf)) == mygen) __builtin_amdgcn_s_sleep(4);
    }
    s_last = last;
  }
  __syncthreads();
  if (s_last){
    tail();
    __syncthreads();
    if (threadIdx.x == 0){
      __builtin_amdgcn_s_waitcnt(0);     // tail's sc1 stores + root reset at L3
#pragma unroll
      for (int l = 0; l < GW/16; ++l) astore(bi + BI_REL(l), mygen + 1);
    }
  }
  __syncthreads();
}

// ================= K1: gi = src_emb @ eWih^T + bih, plus beam-state init =================
__global__ __launch_bounds__(256)
void k_gi(const int* __restrict__ toks, const float* __restrict__ emb,
          const float* __restrict__ eWih, const float* __restrict__ ebih,
          float* __restrict__ ws)
{
  float* fb = ws + 2048;
  float* gi = fb + OF_GI;
  const int tid = threadIdx.x, wid = blockIdx.x, lane = tid & 63, wvi = tid >> 6;
  int Wg = wid*4 + wvi;                 // 0..1023
  for (int it = 0; it < 192; ++it){
    int idx = Wg*192 + it;              // covers 128*1536
    int s = idx / 1536, j = idx - s*1536;
    const float* er = emb + (size_t)toks[s]*H_SZ;
    const float* wr = eWih + (size_t)j*H_SZ;
    float a = 0.f;
#pragma unroll
    for (int u = 0; u < 8; ++u) a += er[u*64+lane]*wr[u*64+lane];
    a = wredsum(a);
    if (lane == 0) gi[idx] = a + ebih[j];
  }
  if (wid == 0){
    float* sc = fb + OF_SC;
    int* ib = (int*)(fb + OI_BASE);
    if (tid < NBEAM){
      sc[tid] = (tid==0) ? 0.f : NEGINF;
      ib[I_TOK+tid] = TOK_SOS; ib[I_FIN+tid] = 0; ib[I_LEN+tid] = 1; ib[I_PAR+tid] = 0;
    }
    for (int q = tid; q < 2*NBEAM*TMAXX; q += 256) ib[I_SEQ+q] = 0;
  }
}

// ================= K2: sequential encoder, 16 WGs, Whh in registers =================
__global__ __launch_bounds__(NT, 1)
void k_enc(const float* __restrict__ eWhh, const float* __restrict__ ebhh,
           float* __restrict__ ws)
{
  int* bi = (int*)ws;
  float* fb = ws + 2048;
  float* gi = fb + OF_GI;
  float* enc = fb + OF_ENC;
  const int tid = threadIdx.x, wid = blockIdx.x, lane = tid & 63, wvi = tid >> 6;
  const int i0 = wid*32;
  __shared__ float smF[96];

  // preload this wave's 12 Whh rows into registers (96 VGPRs/thread)
  float wreg[12][8];
#pragma unroll
  for (int dd = 0; dd < 12; ++dd){
    int d = wvi*12 + dd, g = d >> 5, il = d & 31;
    const float* wr = eWhh + (size_t)(g*512 + i0 + il)*H_SZ;
#pragma unroll
    for (int u = 0; u < 8; ++u) wreg[dd][u] = wr[u*64+lane];
  }
  // persistent bias loads for the epilogue threads
  float eb0 = 0.f, eb1 = 0.f, eb2 = 0.f;
  if (tid < 32){
    int i = i0 + tid;
    eb0 = ebhh[i]; eb1 = ebhh[512+i]; eb2 = ebhh[1024+i];
  }

  for (int s = 0; s < S_SZ; ++s){
    float hreg[8];
    if (s == 0){
#pragma unroll
      for (int u = 0; u < 8; ++u) hreg[u] = 0.f;
    } else {
      const float* hp = enc + (size_t)(s-1)*H_SZ;
#pragma unroll
      for (int u = 0; u < 8; ++u) hreg[u] = aload(hp + u*64 + lane);
    }
#pragma unroll
    for (int dd = 0; dd < 12; ++dd){
      float a = 0.f;
#pragma unroll
      for (int u = 0; u < 8; ++u) a += wreg[dd][u]*hreg[u];
      a = wredsum(a);
      if (lane == 0) smF[wvi*12 + dd] = a;
    }
    __syncthreads();
    if (tid < 32){
      int i = i0 + tid;
      float gr = smF[tid], gz = smF[32+tid], gn = smF[64+tid];
      float gir = gi[s*1536 + i], giz = gi[s*1536 + 512 + i], gin = gi[s*1536 + 1024 + i];
      float hprev = (s==0) ? 0.f : aload(enc + (s-1)*H_SZ + i);
      float r = 1.f/(1.f + expf(-(gir + gr + eb0)));
      float z = 1.f/(1.f + expf(-(giz + gz + eb1)));
      float n = tanhf(gin + r*(gn + eb2));
      astore(enc + s*H_SZ + i, (1.f - z)*n + z*hprev);
    }
    // fence-free 16-WG barrier
    __syncthreads();
    if (tid == 0){
      int g = aload(bi + BI_EREL);
      __builtin_amdgcn_s_waitcnt(0);
      int lo = __hip_atomic_fetch_add(bi + BI_ECNT, 1, __ATOMIC_RELAXED, __HIP_MEMORY_SCOPE_AGENT);
      if (lo == GENC - 1){
        astore(bi + BI_ECNT, 0);
        __builtin_amdgcn_s_waitcnt(0);
        astore(bi + BI_EREL, g + 1);
      } else {
        while (aload(bi + BI_EREL) == g) __builtin_amdgcn_s_sleep(2);
      }
    }
    __syncthreads();
  }
}

// ================= K3: EW = enc_out @ Wc_bottom =================
__global__ __launch_bounds__(NT)
void k_ew(const float* __restrict__ Wc, float* __restrict__ ws)
{
  float* fb = ws + 2048;
  float* enc = fb + OF_ENC;
  float* EW  = fb + OF_EW;
  const int tid = threadIdx.x, wid = blockIdx.x;
  int jc = wid & 15, sb = wid >> 4;
  int jl = tid & 31, sl = (tid >> 5) & 15;
  int s = sb*16 + sl, j = jc*32 + jl;
  const float* er = enc + (size_t)s*H_SZ;       // plain: kernel boundary made it visible
  const float* wc = Wc + (size_t)512*H_SZ;
  float a = 0.f;
  for (int k = 0; k < 512; ++k) a += er[k]*wc[(size_t)k*H_SZ + j];
  EW[s*H_SZ + j] = a;
}

// ================= K4: persistent decode, GW=128, pipelined vocab GEMM =================
__global__ __launch_bounds__(NT, 2)
void k_dec(const float* __restrict__ emb,
           const float* __restrict__ dWih, const float* __restrict__ dWhh,
           const float* __restrict__ dbih, const float* __restrict__ dbhh,
           const float* __restrict__ Wc,  const float* __restrict__ Wv,
           float* __restrict__ out, float* __restrict__ ws)
{
  const int wid = blockIdx.x, tid = threadIdx.x;
  const int lane = tid & 63, wvi = tid >> 6;
  int* bi = (int*)ws;
  float* fb = ws + 2048;
  float* enc  = fb + OF_ENC;
  float* EW   = fb + OF_EW;
  float* h2   = fb + OF_H2;
  float* al   = fb + OF_AL;
  float* otop = fb + OF_OTOP;
  float* pv   = fb + OF_PV;
  float* pm   = fb + OF_PM;
  float* ps   = fb + OF_PS;
  float* sc   = fb + OF_SC;
  int* ib   = (int*)(fb + OI_BASE);
  int* pidx = ib;
  int* tokA = ib + I_TOK;
  int* finA = ib + I_FIN;
  int* lenA = ib + I_LEN;
  int* parA = ib + I_PAR;
  int* seqA = ib + I_SEQ;   // [2][5][32]

  __shared__ float smF[512];
  __shared__ int   smI[256];
  __shared__ float s_buf[2560];   // stage A: h_prev rows; stage B: h2new; stage C: oo
  __shared__ float s_pp[648];     // softmax exp + sums

  // ---- persistent decoder GRU weight rows (all 32 steps): 8 waves x 3 rows x 8 regs ----
  const int i0 = wid*4;
  const int mat = wvi >> 2;                 // waves 0-3: Wih(x); 4-7: Whh(h)
  float wreg3[3][8];
#pragma unroll
  for (int rr = 0; rr < 3; ++rr){
    int R = wvi*3 + rr;                     // 0..23
    int rem = R - mat*12;
    int g = rem >> 2, il = rem & 3;
    const float* wr = ((mat==0) ? dWih : dWhh) + (size_t)(g*512 + i0 + il)*H_SZ;
#pragma unroll
    for (int u = 0; u < 8; ++u) wreg3[rr][u] = wr[u*64+lane];
  }
  // ---- persistent GRU biases for epilogue threads (tid<20) ----
  float pbih0=0.f,pbih1=0.f,pbih2=0.f,pbhh0=0.f,pbhh1=0.f,pbhh2=0.f;
  if (tid < 20){
    int i = i0 + (tid & 3);
    pbih0 = dbih[i]; pbih1 = dbih[512+i]; pbih2 = dbih[1024+i];
    pbhh0 = dbhh[i]; pbhh1 = dbhh[512+i]; pbhh2 = dbhh[1024+i];
  }
  // ---- persistent Wc_top column slice for stage B (tid<320): 32 regs ----
  const int bq   = tid % 20;                // output slot within WG
  const int bksl = tid / 20;                // k-slice 0..15
  const int bf   = wid*20 + bq;             // flat b*512+j
  const int bb   = bf >> 9, bj = bf & 511;
  float wcreg[32];
  if (tid < 320){
#pragma unroll
    for (int u = 0; u < 32; ++u) wcreg[u] = Wc[(size_t)(bksl*32 + u)*H_SZ + bj];
  }

  for (int t = 0; t < TMAXX; ++t){
    float* h2new = h2 + (t & 1)*2560;
    float* h2old = h2 + ((t & 1) ^ 1)*2560;

    // ---- Stage A: decoder GRU (4 hidden columns per WG) ----
    if (tid < NBEAM){ smI[tid] = aload(tokA + tid); smI[8 + tid] = t ? aload(parA + tid) : 0; }
    __syncthreads();
    if (t == 0){
      for (int q = tid; q < 2560; q += NT) s_buf[q] = enc[127*H_SZ + (q & 511)];
    } else {
      for (int q = tid; q < 2560; q += NT){
        int b = q >> 9;
        s_buf[q] = aload(h2old + smI[8 + b]*H_SZ + (q & 511));
      }
    }
    __syncthreads();
    {
      float srg[5][8];
      if (mat == 0){
#pragma unroll
        for (int b = 0; b < NBEAM; ++b){
          const float* sp = emb + (size_t)smI[b]*H_SZ;
#pragma unroll
          for (int u = 0; u < 8; ++u) srg[b][u] = sp[u*64+lane];
        }
      } else {
#pragma unroll
        for (int b = 0; b < NBEAM; ++b)
#pragma unroll
          for (int u = 0; u < 8; ++u) srg[b][u] = s_buf[b*512 + u*64 + lane];
      }
#pragma unroll
      for (int rr = 0; rr < 3; ++rr){
        int R = wvi*3 + rr;                 // 0..23
#pragma unroll
        for (int b = 0; b < NBEAM; ++b){
          float a = 0.f;
#pragma unroll
          for (int u = 0; u < 8; ++u) a += wreg3[rr][u]*srg[b][u];
          a = wredsum(a);
          if (lane == 0) smF[R*5 + b] = a;
        }
      }
      __syncthreads();
      if (tid < 20){
        int b = tid >> 2, il = tid & 3;
        int i = i0 + il;
        float ir  = smF[(0*12 + 0*4 + il)*5 + b] + pbih0;
        float iz  = smF[(0*12 + 1*4 + il)*5 + b] + pbih1;
        float inn = smF[(0*12 + 2*4 + il)*5 + b] + pbih2;
        float hr  = smF[(1*12 + 0*4 + il)*5 + b] + pbhh0;
        float hz  = smF[(1*12 + 1*4 + il)*5 + b] + pbhh1;
        float hn  = smF[(1*12 + 2*4 + il)*5 + b] + pbhh2;
        float r = 1.f/(1.f + expf(-(ir + hr)));
        float z = 1.f/(1.f + expf(-(iz + hz)));
        float n = tanhf(inn + r*hn);
        float hp = s_buf[b*512 + i];
        astore(h2new + b*H_SZ + i, (1.f - z)*n + z*hp);
      }
    }
    dbar(bi, wid, [&](){});

    // ---- Stage B: attention logits (s = wid) + otop = h2 @ Wc_top (persistent Wc regs) ----
    for (int q = tid; q < 2560; q += NT) s_buf[q] = aload(h2new + q);
    __syncthreads();
    if (wvi < NBEAM){
      const float* er = enc + (size_t)wid*H_SZ;
      float a = 0.f;
#pragma unroll
      for (int u = 0; u < 8; ++u) a += er[u*64+lane]*s_buf[wvi*512 + u*64 + lane];
      a = wredsum(a);
      if (lane == 0) astore(al + wvi*S_SZ + wid, a);
    }
    if (tid < 320){
      float a = 0.f;
#pragma unroll
      for (int u = 0; u < 32; ++u) a += s_buf[bb*512 + bksl*32 + u]*wcreg[u];
      smF[bq*16 + bksl] = a;
    }
    __syncthreads();
    if (tid < 20){
      float a = 0.f;
#pragma unroll
      for (int u = 0; u < 16; ++u) a += smF[tid*16 + u];
      astore(otop + wid*20 + tid, a);
    }
    dbar(bi, wid, [&](){});

    // ---- Stage C: local softmax + o, pipelined vocab GEMM, per-WG partials ----
    if (wvi < NBEAM){
      float a1 = aload(al + wvi*S_SZ + lane), a2 = aload(al + wvi*S_SZ + 64 + lane);
      float m = fmaxf(a1, a2);
#pragma unroll
      for (int mm = 32; mm; mm >>= 1) m = fmaxf(m, __shfl_xor(m, mm, 64));
      float e1 = expf(a1 - m), e2 = expf(a2 - m);
      s_pp[wvi*128 + lane] = e1; s_pp[wvi*128 + 64 + lane] = e2;
      float ssv = wredsum(e1 + e2);
      if (lane == 0) s_pp[640 + wvi] = ssv;
    }
    __syncthreads();
    {
      float acc[5] = {0.f,0.f,0.f,0.f,0.f};
      for (int s2 = 0; s2 < 128; ++s2){
        float e = EW[(size_t)s2*H_SZ + tid];
#pragma unroll
        for (int b = 0; b < NBEAM; ++b) acc[b] += e*s_pp[b*128 + s2];
      }
#pragma unroll
      for (int b = 0; b < NBEAM; ++b)
        s_buf[b*512 + tid] = tanhf(aload(otop + b*512 + tid) + acc[b]/s_pp[640 + b]);
    }
    __syncthreads();
    {
      int vbase = wid*COLS_PER_WG;
      int v = vbase + tid;
      bool act = (tid < COLS_PER_WG) && (v < V_SZ);
      int vc = act ? v : vbase;
      const float* wp = Wv + vc;
      float a0=0.f,a1=0.f,a2=0.f,a3=0.f,a4=0.f;
      // software-pipelined: dual 32-deep load buffers, FMA block k overlaps loads k+1
      float wrA[32], wrB[32];
#pragma unroll
      for (int u = 0; u < 32; ++u) wrA[u] = wp[(size_t)u*V_SZ];
      for (int hb = 0; hb < 512; hb += 64){
#pragma unroll
        for (int u = 0; u < 32; ++u) wrB[u] = wp[(size_t)(hb+32+u)*V_SZ];
#pragma unroll
        for (int u = 0; u < 32; ++u){
          float w = wrA[u]; int h = hb + u;
          a0 += w*s_buf[h];
          a1 += w*s_buf[512+h];
          a2 += w*s_buf[1024+h];
          a3 += w*s_buf[1536+h];
          a4 += w*s_buf[2048+h];
        }
        if (hb + 64 < 512){
#pragma unroll
          for (int u = 0; u < 32; ++u) wrA[u] = wp[(size_t)(hb+64+u)*V_SZ];
        }
#pragma unroll
        for (int u = 0; u < 32; ++u){
          float w = wrB[u]; int h = hb + 32 + u;
          a0 += w*s_buf[h];
          a1 += w*s_buf[512+h];
          a2 += w*s_buf[1024+h];
          a3 += w*s_buf[1536+h];
          a4 += w*s_buf[2048+h];
        }
      }
      if (!act){ a0=a1=a2=a3=a4=-3e38f; }
      int myv = act ? v : 0x7FFFFFFF;
      float accs[5] = {a0,a1,a2,a3,a4};
#pragma unroll
      for (int b = 0; b < NBEAM; ++b){
        float x = accs[b];
        float m = x;
#pragma unroll
        for (int mm = 32; mm; mm >>= 1) m = fmaxf(m, __shfl_xor(m, mm, 64));
        float e = expf(x - m);
        float ssum = wredsum(e);
        float bv = x; int bc = myv;
        float w5[5]; int i5[5];
#pragma unroll
        for (int r = 0; r < 5; ++r){
          float cv2 = bv; int ci2 = bc;
#pragma unroll
          for (int mm = 32; mm; mm >>= 1){
            float ov = __shfl_xor(cv2, mm, 64); int oi = __shfl_xor(ci2, mm, 64);
            bool take = (ov > cv2) || (ov == cv2 && oi < ci2);
            cv2 = take ? ov : cv2; ci2 = take ? oi : ci2;
          }
          w5[r] = cv2; i5[r] = ci2;
          if (bc == ci2) bv = -3e38f;
        }
        if (lane == 0){
#pragma unroll
          for (int r = 0; r < 5; ++r){ smF[(wvi*5+b)*5+r] = w5[r]; smI[(wvi*5+b)*5+r] = i5[r]; }
          smF[300 + wvi*5 + b] = m;
          smF[360 + wvi*5 + b] = ssum;
        }
      }
      __syncthreads();
      if (tid < NBEAM){
        float M = -3.4e38f, Sv = 0.f;
#pragma unroll
        for (int w8 = 0; w8 < 8; ++w8){
          float m2 = smF[300 + w8*5 + tid], s2 = smF[360 + w8*5 + tid];
          if (m2 > M){ Sv = Sv*expf(M - m2) + s2; M = m2; }
          else       { Sv = Sv + s2*expf(m2 - M); }
        }
        astore(pm + wid*5 + tid, M); astore(ps + wid*5 + tid, Sv);
      }
      if (wvi < NBEAM){
        int b = wvi;
        float cval; int cidx;
        if (lane < 40){ cval = smF[((lane/5)*5 + b)*5 + (lane%5)]; cidx = smI[((lane/5)*5 + b)*5 + (lane%5)]; }
        else { cval = -3e38f; cidx = 0x7FFFFFFF; }
        float bv = cval; int bc = cidx;
#pragma unroll
        for (int r = 0; r < 5; ++r){
          float cv2 = bv; int ci2 = bc;
#pragma unroll
          for (int mm = 32; mm; mm >>= 1){
            float ov = __shfl_xor(cv2, mm, 64); int oi = __shfl_xor(ci2, mm, 64);
            bool take = (ov > cv2) || (ov == cv2 && oi < ci2);
            cv2 = take ? ov : cv2; ci2 = take ? oi : ci2;
          }
          if (lane == 0){ astore(pv + (wid*5+b)*5+r, cv2); astore(pidx + (wid*5+b)*5+r, ci2); }
          if (bc == ci2) bv = -3e38f;
        }
      }
    }
    dbar(bi, wid, [&](){
      // ======== Stage D (barrier tail, one WG): merge 2x64 WG groups ========
      int b5 = wvi;
      if (b5 < NBEAM){
        float m1 = aload(pm + lane*5 + b5), s1 = aload(ps + lane*5 + b5);
        float m2 = aload(pm + (64+lane)*5 + b5), s2 = aload(ps + (64+lane)*5 + b5);
        float M, Sv;
        if (m1 >= m2){ M = m1; Sv = s1 + s2*expf(m2 - m1); }
        else         { M = m2; Sv = s2 + s1*expf(m1 - m2); }
#pragma unroll
        for (int mm = 32; mm; mm >>= 1){
          float om = __shfl_xor(M, mm, 64), os = __shfl_xor(Sv, mm, 64);
          if (om > M){ Sv = Sv*expf(M - om) + os; M = om; }
          else       { Sv = Sv + os*expf(om - M); }
        }
        if (lane == 0){ smF[8 + b5] = M; smF[80 + b5] = logf(Sv); }
        // prefetch BOTH groups' top-5 lists up-front (independent loads, one L3 latency)
        float lv[5]; int li[5];
        float nv5[5]; int ni5[5];
#pragma unroll
        for (int r = 0; r < 5; ++r){
          lv[r]  = aload(pv + (lane*5 + b5)*5 + r);      li[r]  = aload(pidx + (lane*5 + b5)*5 + r);
          nv5[r] = aload(pv + ((64+lane)*5 + b5)*5 + r); ni5[r] = aload(pidx + ((64+lane)*5 + b5)*5 + r);
        }
        for (int r = 0; r < 5; ++r){
          bool ins = (nv5[r] > lv[4]) || (nv5[r] == lv[4] && ni5[r] < li[4]);
          if (!ins) break;
          lv[4] = nv5[r]; li[4] = ni5[r];
#pragma unroll
          for (int p = 4; p > 0; --p){
            bool sw = (lv[p] > lv[p-1]) || (lv[p] == lv[p-1] && li[p] < li[p-1]);
            if (sw){ float tv = lv[p]; lv[p] = lv[p-1]; lv[p-1] = tv;
                     int ti = li[p]; li[p] = li[p-1]; li[p-1] = ti; }
          }
        }
        float cv = lv[0]; int ci = li[0];
#pragma unroll
        for (int r = 0; r < 5; ++r){
          float xv = cv; int xi = ci;
#pragma unroll
          for (int mm = 32; mm; mm >>= 1){
            float ov = __shfl_xor(xv, mm, 64); int oi = __shfl_xor(xi, mm, 64);
            bool take = (ov > xv) || (ov == xv && oi < xi);
            xv = take ? ov : xv; xi = take ? oi : xi;
          }
          if (lane == 0){ smF[16 + b5*5 + r] = xv; smI[16 + b5*5 + r] = xi; }
          if (ci == xi){
            lv[0]=lv[1]; li[0]=li[1]; lv[1]=lv[2]; li[1]=li[2];
            lv[2]=lv[3]; li[2]=li[3]; lv[3]=lv[4]; li[3]=li[4];
            lv[4] = -3e38f; li[4] = 0x7FFFFFFF;
            cv = lv[0]; ci = li[0];
          }
        }
      }
      __syncthreads();
      if (wvi == 0){
        float cval = -3e38f; int cflat = 0x7FFFFFFF;
        int b = lane/5, k = lane - b*5;
        if (lane < 25){
          if (aload(finA + b)){
            if (k == 0){ cval = aload(sc + b) + 0.0f; cflat = b*V_SZ + TOK_EOS; }
          } else {
            cval = ((smF[16 + b*5 + k] - smF[8 + b]) - smF[80 + b]) + aload(sc + b);
            cflat = b*V_SZ + smI[16 + b*5 + k];
          }
        }
        float bv = cval; int bc = cflat;
#pragma unroll
        for (int r = 0; r < 5; ++r){
          float xv = bv; int xi = bc;
#pragma unroll
          for (int mm = 32; mm; mm >>= 1){
            float ov = __shfl_xor(xv, mm, 64); int oi = __shfl_xor(xi, mm, 64);
            bool take = (ov > xv) || (ov == xv && oi < xi);
            xv = take ? ov : xv; xi = take ? oi : xi;
          }
          if (lane == 0){ smF[48 + r] = xv; smI[48 + r] = xi; }
          if (bc == xi) bv = -3e38f;
        }
        if (lane < NBEAM){
          int r = lane;
          float nscore = smF[48 + r]; int nfl = smI[48 + r];
          int par = nfl / V_SZ; int tok = nfl - par*V_SZ;
          int ofin = aload(finA + par); int olen = aload(lenA + par);  // reads before writes (wave-lockstep)
          int nf = (ofin || tok == TOK_EOS) ? 1 : 0;
          int nl = olen + (ofin ? 0 : 1);
          astore(sc + r, nscore); astore(tokA + r, tok); astore(finA + r, nf);
          astore(lenA + r, nl); astore(parA + r, par);
          smI[56 + r] = par; smI[64 + r] = tok; smI[72 + r] = ofin; smI[80 + r] = nl;
          smF[56 + r] = nscore;
        }
      }
      __syncthreads();
      int cur = t & 1, nxt = 1 - cur;
      if (tid < 160){
        int r = tid >> 5, u = tid & 31;
        int par = smI[56 + r];
        int val = aload(seqA + cur*160 + par*32 + u);
        if (u == t) val = smI[72 + r] ? 0 : smI[64 + r];
        astore(seqA + nxt*160 + r*32 + u, val);
      }
      if (t == TMAXX - 1){
        __syncthreads();
        if (tid == 0){
          float nn[5];
#pragma unroll
          for (int r = 0; r < 5; ++r) nn[r] = smF[56 + r] / (float)smI[80 + r];
          int used = 0;
#pragma unroll
          for (int r = 0; r < 5; ++r){
            int best = -1;
            for (int q2 = 0; q2 < 5; ++q2){
              if (used & (1 << q2)) continue;
              if (best < 0 || nn[q2] > nn[best]) best = q2;
            }
            used |= (1 << best);
            smI[88 + r] = best; smF[64 + r] = nn[best];
          }
        }
        __syncthreads();
        if (tid < 160){
          int r = tid >> 5, u = tid & 31;
          int src = smI[88 + r];
          out[tid] = (float)aload(seqA + nxt*160 + src*32 + u);
        }
        if (tid >= 160 && tid < 165) out[tid] = smF[64 + (tid - 160)];
      }
    });
  }
}

extern "C" void kernel_launch(void* const* d_in, const int* in_sizes, int n_in,
                              void* d_out, int out_size, void* d_ws, size_t ws_size,
                              hipStream_t stream)
{
  (void)in_sizes; (void)n_in; (void)out_size; (void)ws_size;
  hipMemsetAsync(d_ws, 0, 8192, stream);   // barrier counters/generations
  float* ws = (float*)d_ws;
  k_gi<<<dim3(256), dim3(256), 0, stream>>>(
      (const int*)d_in[0], (const float*)d_in[1],
      (const float*)d_in[2], (const float*)d_in[4], ws);
  k_enc<<<dim3(GENC), dim3(NT), 0, stream>>>(
      (const float*)d_in[3], (const float*)d_in[5], ws);
  k_ew<<<dim3(128), dim3(NT), 0, stream>>>(
      (const float*)d_in[10], ws);
  k_dec<<<dim3(GW), dim3(NT), 0, stream>>>(
      (const float*)d_in[1],
      (const float*)d_in[6], (const float*)d_in[7],
      (const float*)d_in[8], (const float*)d_in[9],
      (const float*)d_in[10], (const float*)d_in[11],
      (float*)d_out, ws);
}

// Round 3
// 4329.304 us; speedup vs baseline: 1.4925x; 1.4925x over previous
//
#include <hip/hip_runtime.h>
#include <cstdint>
#include <cstddef>

// ---------------- problem constants ----------------
#define V_SZ 50257
#define H_SZ 512
#define S_SZ 128
#define NBEAM 5
#define TMAXX 32
#define TOK_SOS 1
#define TOK_EOS 2
#define NEGINF (-1e9f)

// ---------------- launch shape ----------------
#define GW 128            // decode workgroups (measured best; 256 regressed: sync/serial cost)
#define NT 512
#define GENC 16           // encoder WGs (Whh register-resident)
#define COLS_PER_WG 393   // ceil(V/GW) for the scalar fallback path

// ---------------- packed-Wv (float4) path ----------------
#define VPAD 51200        // 128 WG * 400 cols, mult of 4
#define CW4  400          // cols per WG (packed path)
#define WVP_OFF 1048576   // float offset of packed Wv inside ws (4 MiB)
#define WS_NEED (4194304ull + (size_t)H_SZ*VPAD*4ull)   // bytes required for packed path

// ---------------- barrier ints (start of ws; first 8 KiB memset to 0) ----------------
#define BI_LEAF(l)  ((l)*32)        // 8 leaf counters (16 WGs each)
#define BI_ROOT     544
#define BI_REL(l)   (1024 + (l)*32) // 8 per-leaf release generations
#define BI_ECNT     1792
#define BI_EREL     1824

// ---------------- float region: fb = (float*)ws + 2048 ----------------
#define OF_GI    0            // 128*1536
#define OF_ENC   196608       // 128*512
#define OF_EW    262144       // 128*512  enc_out @ Wc_bottom
#define OF_H2    327680       // [2][5][512] ping-pong decoder hidden
#define OF_AL    332800       // [5][128] attention logits
#define OF_OTOP  333440       // [5][512] h2 @ Wc_top (flat b*512+j)
#define OF_PV    336000       // [<=256][5][5]
#define OF_PM    342400       // [<=256][5]
#define OF_PS    343680       // [<=256][5]
#define OF_SC    344960       // [8]
#define OI_BASE  344968
#define I_TOK 6400
#define I_FIN 6408
#define I_LEN 6416
#define I_PAR 6424
#define I_SEQ 6432

template <typename T>
__device__ __forceinline__ T aload(const T* p){
  return __hip_atomic_load((T*)p, __ATOMIC_RELAXED, __HIP_MEMORY_SCOPE_AGENT);
}
template <typename T>
__device__ __forceinline__ void astore(T* p, T v){
  __hip_atomic_store(p, v, __ATOMIC_RELAXED, __HIP_MEMORY_SCOPE_AGENT);
}

__device__ __forceinline__ float wredsum(float a){
#pragma unroll
  for (int m = 32; m; m >>= 1) a += __shfl_xor(a, m, 64);
  return a;
}

// fence-free device barrier over GW WGs; last-arriving WG runs tail() before release.
template <typename F>
__device__ __forceinline__ void dbar(int* bi, int wid, F&& tail){
  __shared__ int s_last;
  int mygen = 0;
  __syncthreads();
  if (threadIdx.x == 0){
    int leaf = wid >> 4;
    mygen = aload(bi + BI_REL(leaf));
    __builtin_amdgcn_s_waitcnt(0);
    int lo = __hip_atomic_fetch_add(bi + BI_LEAF(leaf), 1, __ATOMIC_RELAXED, __HIP_MEMORY_SCOPE_AGENT);
    int last = 0;
    if (lo == 15){
      astore(bi + BI_LEAF(leaf), 0);
      __builtin_amdgcn_s_waitcnt(0);     // leaf reset at L3 before root arrive
      int ro = __hip_atomic_fetch_add(bi + BI_ROOT, 1, __ATOMIC_RELAXED, __HIP_MEMORY_SCOPE_AGENT);
      if (ro == (GW/16) - 1){
        astore(bi + BI_ROOT, 0);
        last = 1;
      }
    }
    if (!last){
      while (aload(bi + BI_REL(leaf)) == mygen) __builtin_amdgcn_s_sleep(4);
    }
    s_last = last;
  }
  __syncthreads();
  if (s_last){
    tail();
    __syncthreads();
    if (threadIdx.x == 0){
      __builtin_amdgcn_s_waitcnt(0);     // tail's sc1 stores + root reset at L3
#pragma unroll
      for (int l = 0; l < GW/16; ++l) astore(bi + BI_REL(l), mygen + 1);
    }
  }
  __syncthreads();
}

// ================= K0: pack Wv into padded [512][VPAD] for float4 streaming =================
__global__ __launch_bounds__(256)
void k_pack(const float* __restrict__ Wv, float* __restrict__ ws)
{
  float* wvp = ws + WVP_OFF;
  const int h  = blockIdx.y;
  const int v4 = blockIdx.x*256 + threadIdx.x;      // 0..12799
  const int v  = v4*4;
  const float* src = Wv + (size_t)h*V_SZ;
  float4 o;
  o.x = (v+0 < V_SZ) ? src[v+0] : 0.f;
  o.y = (v+1 < V_SZ) ? src[v+1] : 0.f;
  o.z = (v+2 < V_SZ) ? src[v+2] : 0.f;
  o.w = (v+3 < V_SZ) ? src[v+3] : 0.f;
  *(float4*)(wvp + (size_t)h*VPAD + v) = o;
}

// ================= K1: gi = src_emb @ eWih^T + bih, plus beam-state init =================
__global__ __launch_bounds__(256)
void k_gi(const int* __restrict__ toks, const float* __restrict__ emb,
          const float* __restrict__ eWih, const float* __restrict__ ebih,
          float* __restrict__ ws)
{
  float* fb = ws + 2048;
  float* gi = fb + OF_GI;
  const int tid = threadIdx.x, wid = blockIdx.x, lane = tid & 63, wvi = tid >> 6;
  int Wg = wid*4 + wvi;                 // 0..1023
  for (int it = 0; it < 192; ++it){
    int idx = Wg*192 + it;              // covers 128*1536
    int s = idx / 1536, j = idx - s*1536;
    const float* er = emb + (size_t)toks[s]*H_SZ;
    const float* wr = eWih + (size_t)j*H_SZ;
    float a = 0.f;
#pragma unroll
    for (int u = 0; u < 8; ++u) a += er[u*64+lane]*wr[u*64+lane];
    a = wredsum(a);
    if (lane == 0) gi[idx] = a + ebih[j];
  }
  if (wid == 0){
    float* sc = fb + OF_SC;
    int* ib = (int*)(fb + OI_BASE);
    if (tid < NBEAM){
      sc[tid] = (tid==0) ? 0.f : NEGINF;
      ib[I_TOK+tid] = TOK_SOS; ib[I_FIN+tid] = 0; ib[I_LEN+tid] = 1; ib[I_PAR+tid] = 0;
    }
    for (int q = tid; q < 2*NBEAM*TMAXX; q += 256) ib[I_SEQ+q] = 0;
  }
}

// ================= K2: sequential encoder, 16 WGs, Whh in registers =================
__global__ __launch_bounds__(NT, 1)
void k_enc(const float* __restrict__ eWhh, const float* __restrict__ ebhh,
           float* __restrict__ ws)
{
  int* bi = (int*)ws;
  float* fb = ws + 2048;
  float* gi = fb + OF_GI;
  float* enc = fb + OF_ENC;
  const int tid = threadIdx.x, wid = blockIdx.x, lane = tid & 63, wvi = tid >> 6;
  const int i0 = wid*32;
  __shared__ float smF[96];

  // preload this wave's 12 Whh rows into registers (96 VGPRs/thread)
  float wreg[12][8];
#pragma unroll
  for (int dd = 0; dd < 12; ++dd){
    int d = wvi*12 + dd, g = d >> 5, il = d & 31;
    const float* wr = eWhh + (size_t)(g*512 + i0 + il)*H_SZ;
#pragma unroll
    for (int u = 0; u < 8; ++u) wreg[dd][u] = wr[u*64+lane];
  }
  float eb0 = 0.f, eb1 = 0.f, eb2 = 0.f;
  if (tid < 32){
    int i = i0 + tid;
    eb0 = ebhh[i]; eb1 = ebhh[512+i]; eb2 = ebhh[1024+i];
  }

  for (int s = 0; s < S_SZ; ++s){
    float hreg[8];
    if (s == 0){
#pragma unroll
      for (int u = 0; u < 8; ++u) hreg[u] = 0.f;
    } else {
      const float* hp = enc + (size_t)(s-1)*H_SZ;
#pragma unroll
      for (int u = 0; u < 8; ++u) hreg[u] = aload(hp + u*64 + lane);
    }
#pragma unroll
    for (int dd = 0; dd < 12; ++dd){
      float a = 0.f;
#pragma unroll
      for (int u = 0; u < 8; ++u) a += wreg[dd][u]*hreg[u];
      a = wredsum(a);
      if (lane == 0) smF[wvi*12 + dd] = a;
    }
    __syncthreads();
    if (tid < 32){
      int i = i0 + tid;
      float gr = smF[tid], gz = smF[32+tid], gn = smF[64+tid];
      float gir = gi[s*1536 + i], giz = gi[s*1536 + 512 + i], gin = gi[s*1536 + 1024 + i];
      float hprev = (s==0) ? 0.f : aload(enc + (s-1)*H_SZ + i);
      float r = 1.f/(1.f + expf(-(gir + gr + eb0)));
      float z = 1.f/(1.f + expf(-(giz + gz + eb1)));
      float n = tanhf(gin + r*(gn + eb2));
      astore(enc + s*H_SZ + i, (1.f - z)*n + z*hprev);
    }
    // fence-free 16-WG barrier
    __syncthreads();
    if (tid == 0){
      int g = aload(bi + BI_EREL);
      __builtin_amdgcn_s_waitcnt(0);
      int lo = __hip_atomic_fetch_add(bi + BI_ECNT, 1, __ATOMIC_RELAXED, __HIP_MEMORY_SCOPE_AGENT);
      if (lo == GENC - 1){
        astore(bi + BI_ECNT, 0);
        __builtin_amdgcn_s_waitcnt(0);
        astore(bi + BI_EREL, g + 1);
      } else {
        while (aload(bi + BI_EREL) == g) __builtin_amdgcn_s_sleep(2);
      }
    }
    __syncthreads();
  }
}

// ================= K3: EW = enc_out @ Wc_bottom =================
__global__ __launch_bounds__(NT)
void k_ew(const float* __restrict__ Wc, float* __restrict__ ws)
{
  float* fb = ws + 2048;
  float* enc = fb + OF_ENC;
  float* EW  = fb + OF_EW;
  const int tid = threadIdx.x, wid = blockIdx.x;
  int jc = wid & 15, sb = wid >> 4;
  int jl = tid & 31, sl = (tid >> 5) & 15;
  int s = sb*16 + sl, j = jc*32 + jl;
  const float* er = enc + (size_t)s*H_SZ;
  const float* wc = Wc + (size_t)512*H_SZ;
  float a = 0.f;
  for (int k = 0; k < 512; ++k) a += er[k]*wc[(size_t)k*H_SZ + j];
  EW[s*H_SZ + j] = a;
}

// ================= K4: persistent decode; PACKED=1 uses float4 Wv stream =================
template<int PACKED>
__global__ __launch_bounds__(NT, 1)
void k_dec(const float* __restrict__ emb,
           const float* __restrict__ dWih, const float* __restrict__ dWhh,
           const float* __restrict__ dbih, const float* __restrict__ dbhh,
           const float* __restrict__ Wc,  const float* __restrict__ Wv,
           float* __restrict__ out, float* __restrict__ ws)
{
  const int wid = blockIdx.x, tid = threadIdx.x;
  const int lane = tid & 63, wvi = tid >> 6;
  int* bi = (int*)ws;
  float* fb = ws + 2048;
  float* enc  = fb + OF_ENC;
  float* EW   = fb + OF_EW;
  float* h2   = fb + OF_H2;
  float* al   = fb + OF_AL;
  float* otop = fb + OF_OTOP;
  float* pv   = fb + OF_PV;
  float* pm   = fb + OF_PM;
  float* ps   = fb + OF_PS;
  float* sc   = fb + OF_SC;
  int* ib   = (int*)(fb + OI_BASE);
  int* pidx = ib;
  int* tokA = ib + I_TOK;
  int* finA = ib + I_FIN;
  int* lenA = ib + I_LEN;
  int* parA = ib + I_PAR;
  int* seqA = ib + I_SEQ;   // [2][5][32]

  __shared__ float smF[512];
  __shared__ int   smI[256];
  __shared__ float s_buf[2560];   // stage A: h_prev rows; stage B: h2new; stage C: oo
  __shared__ float s_pp[648];     // softmax exp + sums
  __shared__ float s_red[PACKED ? 6300 : 4];   // packed path: H-slice partials (stride 21)

  const int i0 = wid*4;

  for (int t = 0; t < TMAXX; ++t){
    float* h2new = h2 + (t & 1)*2560;
    float* h2old = h2 + ((t & 1) ^ 1)*2560;

    // ---- Stage A: decoder GRU (4 hidden columns per WG) ----
    if (tid < NBEAM){ smI[tid] = aload(tokA + tid); smI[8 + tid] = t ? aload(parA + tid) : 0; }
    __syncthreads();
    if (t == 0){
      for (int q = tid; q < 2560; q += NT) s_buf[q] = enc[127*H_SZ + (q & 511)];
    } else {
      for (int q = tid; q < 2560; q += NT){
        int b = q >> 9;
        s_buf[q] = aload(h2old + smI[8 + b]*H_SZ + (q & 511));
      }
    }
    __syncthreads();
    {
      int mat = wvi >> 2;                       // waves 0-3: Wih(x); 4-7: Whh(h)
      float srg[5][8];
      if (mat == 0){
#pragma unroll
        for (int b = 0; b < NBEAM; ++b){
          const float* sp = emb + (size_t)smI[b]*H_SZ;
#pragma unroll
          for (int u = 0; u < 8; ++u) srg[b][u] = sp[u*64+lane];
        }
      } else {
#pragma unroll
        for (int b = 0; b < NBEAM; ++b)
#pragma unroll
          for (int u = 0; u < 8; ++u) srg[b][u] = s_buf[b*512 + u*64 + lane];
      }
      for (int rr = 0; rr < 3; ++rr){
        int R = wvi*3 + rr;                     // 0..23
        int rem = R - mat*12;
        int g = rem >> 2, il = rem & 3;
        const float* wr = ((mat==0) ? dWih : dWhh) + (size_t)(g*512 + i0 + il)*H_SZ;
        float wreg[8];
#pragma unroll
        for (int u = 0; u < 8; ++u) wreg[u] = wr[u*64+lane];
#pragma unroll
        for (int b = 0; b < NBEAM; ++b){
          float a = 0.f;
#pragma unroll
          for (int u = 0; u < 8; ++u) a += wreg[u]*srg[b][u];
          a = wredsum(a);
          if (lane == 0) smF[R*5 + b] = a;
        }
      }
      __syncthreads();
      if (tid < 20){
        int b = tid >> 2, il = tid & 3;
        int i = i0 + il;
        float ir  = smF[(0*12 + 0*4 + il)*5 + b] + dbih[i];
        float iz  = smF[(0*12 + 1*4 + il)*5 + b] + dbih[512+i];
        float inn = smF[(0*12 + 2*4 + il)*5 + b] + dbih[1024+i];
        float hr  = smF[(1*12 + 0*4 + il)*5 + b] + dbhh[i];
        float hz  = smF[(1*12 + 1*4 + il)*5 + b] + dbhh[512+i];
        float hn  = smF[(1*12 + 2*4 + il)*5 + b] + dbhh[1024+i];
        float r = 1.f/(1.f + expf(-(ir + hr)));
        float z = 1.f/(1.f + expf(-(iz + hz)));
        float n = tanhf(inn + r*hn);
        float hp = s_buf[b*512 + i];
        astore(h2new + b*H_SZ + i, (1.f - z)*n + z*hp);
      }
    }
    dbar(bi, wid, [&](){});

    // ---- Stage B: attention logits (s = wid) + otop = h2 @ Wc_top ----
    for (int q = tid; q < 2560; q += NT) s_buf[q] = aload(h2new + q);
    __syncthreads();
    if (wvi < NBEAM){
      const float* er = enc + (size_t)wid*H_SZ;
      float a = 0.f;
#pragma unroll
      for (int u = 0; u < 8; ++u) a += er[u*64+lane]*s_buf[wvi*512 + u*64 + lane];
      a = wredsum(a);
      if (lane == 0) astore(al + wvi*S_SZ + wid, a);
    }
    if (tid < 320){
      int q = tid % 20, ksl = tid / 20;
      int f = wid*20 + q;
      int b = f >> 9, j = f & 511;
      float a = 0.f;
#pragma unroll 8
      for (int u = 0; u < 32; ++u){
        int k = ksl*32 + u;
        a += s_buf[b*512 + k]*Wc[(size_t)k*H_SZ + j];
      }
      smF[q*16 + ksl] = a;
    }
    __syncthreads();
    if (tid < 20){
      float a = 0.f;
#pragma unroll
      for (int u = 0; u < 16; ++u) a += smF[tid*16 + u];
      astore(otop + wid*20 + tid, a);
    }
    dbar(bi, wid, [&](){});

    // ---- Stage C: local softmax + o, vocab GEMM, per-WG partials ----
    if (wvi < NBEAM){
      float a1 = aload(al + wvi*S_SZ + lane), a2 = aload(al + wvi*S_SZ + 64 + lane);
      float m = fmaxf(a1, a2);
#pragma unroll
      for (int mm = 32; mm; mm >>= 1) m = fmaxf(m, __shfl_xor(m, mm, 64));
      float e1 = expf(a1 - m), e2 = expf(a2 - m);
      s_pp[wvi*128 + lane] = e1; s_pp[wvi*128 + 64 + lane] = e2;
      float ssv = wredsum(e1 + e2);
      if (lane == 0) s_pp[640 + wvi] = ssv;
    }
    __syncthreads();
    {
      float acc[5] = {0.f,0.f,0.f,0.f,0.f};
      for (int s2 = 0; s2 < 128; ++s2){
        float e = EW[(size_t)s2*H_SZ + tid];
#pragma unroll
        for (int b = 0; b < NBEAM; ++b) acc[b] += e*s_pp[b*128 + s2];
      }
#pragma unroll
      for (int b = 0; b < NBEAM; ++b)
        s_buf[b*512 + tid] = tanhf(aload(otop + b*512 + tid) + acc[b]/s_pp[640 + b]);
    }
    __syncthreads();

    if constexpr (PACKED){
      // ======== float4-packed vocab GEMM: 400 cols/WG, 4 H-slices, 8+8 pipeline ========
      const float* wvp = (const float*)(ws + WVP_OFF);
      const int c4 = tid % 100, slice = tid / 100;     // tid<400 active
      float acc[5][4];
#pragma unroll
      for (int b = 0; b < 5; ++b)
#pragma unroll
        for (int k = 0; k < 4; ++k) acc[b][k] = 0.f;
      if (tid < 400){
        const float* wp = wvp + (size_t)(slice*128)*VPAD + wid*CW4 + c4*4;
        const int hbase = slice*128;
        float4 bufA[8], bufB[8];
#pragma unroll
        for (int u = 0; u < 8; ++u) bufA[u] = *(const float4*)(wp + (size_t)u*VPAD);
        for (int hb = 0; hb < 128; hb += 16){
#pragma unroll
          for (int u = 0; u < 8; ++u) bufB[u] = *(const float4*)(wp + (size_t)(hb+8+u)*VPAD);
#pragma unroll
          for (int u = 0; u < 8; ++u){
            float4 w = bufA[u]; int h = hbase + hb + u;
#pragma unroll
            for (int b = 0; b < 5; ++b){
              float o = s_buf[b*512 + h];
              acc[b][0] += w.x*o; acc[b][1] += w.y*o; acc[b][2] += w.z*o; acc[b][3] += w.w*o;
            }
          }
          if (hb + 16 < 128){
#pragma unroll
            for (int u = 0; u < 8; ++u) bufA[u] = *(const float4*)(wp + (size_t)(hb+16+u)*VPAD);
          }
#pragma unroll
          for (int u = 0; u < 8; ++u){
            float4 w = bufB[u]; int h = hbase + hb + 8 + u;
#pragma unroll
            for (int b = 0; b < 5; ++b){
              float o = s_buf[b*512 + h];
              acc[b][0] += w.x*o; acc[b][1] += w.y*o; acc[b][2] += w.z*o; acc[b][3] += w.w*o;
            }
          }
        }
      }
      // H-slice reduction through LDS (stride 21: conflict-free)
      if (tid < 400 && slice > 0){
        float* rp = s_red + (slice-1)*2100 + c4*21;
#pragma unroll
        for (int b = 0; b < 5; ++b)
#pragma unroll
          for (int k = 0; k < 4; ++k) rp[b*4+k] = acc[b][k];
      }
      __syncthreads();
      if (wvi < 2){
        if (tid < 100){
#pragma unroll
          for (int s = 0; s < 3; ++s){
            const float* rp = s_red + s*2100 + tid*21;
#pragma unroll
            for (int b = 0; b < 5; ++b)
#pragma unroll
              for (int k = 0; k < 4; ++k) acc[b][k] += rp[b*4+k];
          }
        }
        int vb4 = wid*CW4 + tid*4;
        bool okk[4];
#pragma unroll
        for (int k = 0; k < 4; ++k) okk[k] = (tid < 100) && (vb4 + k < V_SZ);
#pragma unroll
        for (int b = 0; b < NBEAM; ++b){
          float x[4]; int id[4];
#pragma unroll
          for (int k = 0; k < 4; ++k){
            x[k]  = okk[k] ? acc[b][k] : -3e38f;
            id[k] = okk[k] ? vb4 + k   : 0x7FFFFFFF;
          }
          float m = fmaxf(fmaxf(x[0],x[1]), fmaxf(x[2],x[3]));
#pragma unroll
          for (int mm = 32; mm; mm >>= 1) m = fmaxf(m, __shfl_xor(m, mm, 64));
          float e = 0.f;
#pragma unroll
          for (int k = 0; k < 4; ++k) e += expf(x[k] - m);
          float ssum = wredsum(e);
          float w5[5]; int i5[5];
#pragma unroll
          for (int r = 0; r < 5; ++r){
            float bv = x[0]; int bix = id[0];
#pragma unroll
            for (int k = 1; k < 4; ++k){
              bool take = (x[k] > bv) || (x[k] == bv && id[k] < bix);
              bv = take ? x[k] : bv; bix = take ? id[k] : bix;
            }
#pragma unroll
            for (int mm = 32; mm; mm >>= 1){
              float ov = __shfl_xor(bv, mm, 64); int oi = __shfl_xor(bix, mm, 64);
              bool take = (ov > bv) || (ov == bv && oi < bix);
              bv = take ? ov : bv; bix = take ? oi : bix;
            }
            w5[r] = bv; i5[r] = bix;
#pragma unroll
            for (int k = 0; k < 4; ++k)
              if (id[k] == bix){ x[k] = -3e38f; id[k] = 0x7FFFFFFF; }
          }
          if (lane == 0){
#pragma unroll
            for (int r = 0; r < 5; ++r){ smF[(wvi*5+b)*5+r] = w5[r]; smI[(wvi*5+b)*5+r] = i5[r]; }
            smF[300 + wvi*5 + b] = m;
            smF[360 + wvi*5 + b] = ssum;
          }
        }
      }
      __syncthreads();
      if (tid < NBEAM){
        float M = -3.4e38f, Sv = 0.f;
#pragma unroll
        for (int w8 = 0; w8 < 2; ++w8){
          float m2 = smF[300 + w8*5 + tid], s2 = smF[360 + w8*5 + tid];
          if (m2 > M){ Sv = Sv*expf(M - m2) + s2; M = m2; }
          else       { Sv = Sv + s2*expf(m2 - M); }
        }
        astore(pm + wid*5 + tid, M); astore(ps + wid*5 + tid, Sv);
      }
      if (wvi < NBEAM){
        int b = wvi;
        float cval; int cidx;
        if (lane < 10){ cval = smF[((lane/5)*5 + b)*5 + (lane%5)]; cidx = smI[((lane/5)*5 + b)*5 + (lane%5)]; }
        else { cval = -3e38f; cidx = 0x7FFFFFFF; }
        float bv = cval; int bc = cidx;
#pragma unroll
        for (int r = 0; r < 5; ++r){
          float cv2 = bv; int ci2 = bc;
#pragma unroll
          for (int mm = 32; mm; mm >>= 1){
            float ov = __shfl_xor(cv2, mm, 64); int oi = __shfl_xor(ci2, mm, 64);
            bool take = (ov > cv2) || (ov == cv2 && oi < ci2);
            cv2 = take ? ov : cv2; ci2 = take ? oi : ci2;
          }
          if (lane == 0){ astore(pv + (wid*5+b)*5+r, cv2); astore(pidx + (wid*5+b)*5+r, ci2); }
          if (bc == ci2) bv = -3e38f;
        }
      }
    } else {
      // ======== scalar fallback vocab GEMM (round-0 structure, known-good) ========
      int vbase = wid*COLS_PER_WG;
      int v = vbase + tid;
      bool act = (tid < COLS_PER_WG) && (v < V_SZ);
      int vc = act ? v : vbase;
      const float* wp = Wv + vc;
      float a0=0.f,a1=0.f,a2=0.f,a3=0.f,a4=0.f;
      for (int hb = 0; hb < H_SZ; hb += 16){
        float wr[16];
#pragma unroll
        for (int u = 0; u < 16; ++u) wr[u] = wp[(size_t)(hb+u)*V_SZ];
#pragma unroll
        for (int u = 0; u < 16; ++u){
          float w = wr[u];
          a0 += w*s_buf[hb+u];
          a1 += w*s_buf[512+hb+u];
          a2 += w*s_buf[1024+hb+u];
          a3 += w*s_buf[1536+hb+u];
          a4 += w*s_buf[2048+hb+u];
        }
      }
      if (!act){ a0=a1=a2=a3=a4=-3e38f; }
      int myv = act ? v : 0x7FFFFFFF;
      float accs[5] = {a0,a1,a2,a3,a4};
#pragma unroll
      for (int b = 0; b < NBEAM; ++b){
        float x = accs[b];
        float m = x;
#pragma unroll
        for (int mm = 32; mm; mm >>= 1) m = fmaxf(m, __shfl_xor(m, mm, 64));
        float e = expf(x - m);
        float ssum = wredsum(e);
        float bv = x; int bc = myv;
        float w5[5]; int i5[5];
#pragma unroll
        for (int r = 0; r < 5; ++r){
          float cv2 = bv; int ci2 = bc;
#pragma unroll
          for (int mm = 32; mm; mm >>= 1){
            float ov = __shfl_xor(cv2, mm, 64); int oi = __shfl_xor(ci2, mm, 64);
            bool take = (ov > cv2) || (ov == cv2 && oi < ci2);
            cv2 = take ? ov : cv2; ci2 = take ? oi : ci2;
          }
          w5[r] = cv2; i5[r] = ci2;
          if (bc == ci2) bv = -3e38f;
        }
        if (lane == 0){
#pragma unroll
          for (int r = 0; r < 5; ++r){ smF[(wvi*5+b)*5+r] = w5[r]; smI[(wvi*5+b)*5+r] = i5[r]; }
          smF[300 + wvi*5 + b] = m;
          smF[360 + wvi*5 + b] = ssum;
        }
      }
      __syncthreads();
      if (tid < NBEAM){
        float M = -3.4e38f, Sv = 0.f;
#pragma unroll
        for (int w8 = 0; w8 < 8; ++w8){
          float m2 = smF[300 + w8*5 + tid], s2 = smF[360 + w8*5 + tid];
          if (m2 > M){ Sv = Sv*expf(M - m2) + s2; M = m2; }
          else       { Sv = Sv + s2*expf(m2 - M); }
        }
        astore(pm + wid*5 + tid, M); astore(ps + wid*5 + tid, Sv);
      }
      if (wvi < NBEAM){
        int b = wvi;
        float cval; int cidx;
        if (lane < 40){ cval = smF[((lane/5)*5 + b)*5 + (lane%5)]; cidx = smI[((lane/5)*5 + b)*5 + (lane%5)]; }
        else { cval = -3e38f; cidx = 0x7FFFFFFF; }
        float bv = cval; int bc = cidx;
#pragma unroll
        for (int r = 0; r < 5; ++r){
          float cv2 = bv; int ci2 = bc;
#pragma unroll
          for (int mm = 32; mm; mm >>= 1){
            float ov = __shfl_xor(cv2, mm, 64); int oi = __shfl_xor(ci2, mm, 64);
            bool take = (ov > cv2) || (ov == cv2 && oi < ci2);
            cv2 = take ? ov : cv2; ci2 = take ? oi : ci2;
          }
          if (lane == 0){ astore(pv + (wid*5+b)*5+r, cv2); astore(pidx + (wid*5+b)*5+r, ci2); }
          if (bc == ci2) bv = -3e38f;
        }
      }
    }

    dbar(bi, wid, [&](){
      // ======== Stage D (barrier tail, one WG): merge 2x64 WG groups ========
      int b5 = wvi;
      if (b5 < NBEAM){
        float m1 = aload(pm + lane*5 + b5), s1 = aload(ps + lane*5 + b5);
        float m2 = aload(pm + (64+lane)*5 + b5), s2 = aload(ps + (64+lane)*5 + b5);
        float M, Sv;
        if (m1 >= m2){ M = m1; Sv = s1 + s2*expf(m2 - m1); }
        else         { M = m2; Sv = s2 + s1*expf(m1 - m2); }
#pragma unroll
        for (int mm = 32; mm; mm >>= 1){
          float om = __shfl_xor(M, mm, 64), os = __shfl_xor(Sv, mm, 64);
          if (om > M){ Sv = Sv*expf(M - om) + os; M = om; }
          else       { Sv = Sv + os*expf(om - M); }
        }
        if (lane == 0){ smF[8 + b5] = M; smF[80 + b5] = logf(Sv); }
        // prefetch BOTH groups' top-5 lists up-front (independent loads, one L3 latency)
        float lv[5]; int li[5];
        float nv5[5]; int ni5[5];
#pragma unroll
        for (int r = 0; r < 5; ++r){
          lv[r]  = aload(pv + (lane*5 + b5)*5 + r);      li[r]  = aload(pidx + (lane*5 + b5)*5 + r);
          nv5[r] = aload(pv + ((64+lane)*5 + b5)*5 + r); ni5[r] = aload(pidx + ((64+lane)*5 + b5)*5 + r);
        }
        for (int r = 0; r < 5; ++r){
          bool ins = (nv5[r] > lv[4]) || (nv5[r] == lv[4] && ni5[r] < li[4]);
          if (!ins) break;
          lv[4] = nv5[r]; li[4] = ni5[r];
#pragma unroll
          for (int p = 4; p > 0; --p){
            bool sw = (lv[p] > lv[p-1]) || (lv[p] == lv[p-1] && li[p] < li[p-1]);
            if (sw){ float tv = lv[p]; lv[p] = lv[p-1]; lv[p-1] = tv;
                     int ti = li[p]; li[p] = li[p-1]; li[p-1] = ti; }
          }
        }
        float cv = lv[0]; int ci = li[0];
#pragma unroll
        for (int r = 0; r < 5; ++r){
          float xv = cv; int xi = ci;
#pragma unroll
          for (int mm = 32; mm; mm >>= 1){
            float ov = __shfl_xor(xv, mm, 64); int oi = __shfl_xor(xi, mm, 64);
            bool take = (ov > xv) || (ov == xv && oi < xi);
            xv = take ? ov : xv; xi = take ? oi : xi;
          }
          if (lane == 0){ smF[16 + b5*5 + r] = xv; smI[16 + b5*5 + r] = xi; }
          if (ci == xi){
            lv[0]=lv[1]; li[0]=li[1]; lv[1]=lv[2]; li[1]=li[2];
            lv[2]=lv[3]; li[2]=li[3]; lv[3]=lv[4]; li[3]=li[4];
            lv[4] = -3e38f; li[4] = 0x7FFFFFFF;
            cv = lv[0]; ci = li[0];
          }
        }
      }
      __syncthreads();
      if (wvi == 0){
        float cval = -3e38f; int cflat = 0x7FFFFFFF;
        int b = lane/5, k = lane - b*5;
        if (lane < 25){
          if (aload(finA + b)){
            if (k == 0){ cval = aload(sc + b) + 0.0f; cflat = b*V_SZ + TOK_EOS; }
          } else {
            cval = ((smF[16 + b*5 + k] - smF[8 + b]) - smF[80 + b]) + aload(sc + b);
            cflat = b*V_SZ + smI[16 + b*5 + k];
          }
        }
        float bv = cval; int bc = cflat;
#pragma unroll
        for (int r = 0; r < 5; ++r){
          float xv = bv; int xi = bc;
#pragma unroll
          for (int mm = 32; mm; mm >>= 1){
            float ov = __shfl_xor(xv, mm, 64); int oi = __shfl_xor(xi, mm, 64);
            bool take = (ov > xv) || (ov == xv && oi < xi);
            xv = take ? ov : xv; xi = take ? oi : xi;
          }
          if (lane == 0){ smF[48 + r] = xv; smI[48 + r] = xi; }
          if (bc == xi) bv = -3e38f;
        }
        if (lane < NBEAM){
          int r = lane;
          float nscore = smF[48 + r]; int nfl = smI[48 + r];
          int par = nfl / V_SZ; int tok = nfl - par*V_SZ;
          int ofin = aload(finA + par); int olen = aload(lenA + par);  // reads before writes (wave-lockstep)
          int nf = (ofin || tok == TOK_EOS) ? 1 : 0;
          int nl = olen + (ofin ? 0 : 1);
          astore(sc + r, nscore); astore(tokA + r, tok); astore(finA + r, nf);
          astore(lenA + r, nl); astore(parA + r, par);
          smI[56 + r] = par; smI[64 + r] = tok; smI[72 + r] = ofin; smI[80 + r] = nl;
          smF[56 + r] = nscore;
        }
      }
      __syncthreads();
      int cur = t & 1, nxt = 1 - cur;
      if (tid < 160){
        int r = tid >> 5, u = tid & 31;
        int par = smI[56 + r];
        int val = aload(seqA + cur*160 + par*32 + u);
        if (u == t) val = smI[72 + r] ? 0 : smI[64 + r];
        astore(seqA + nxt*160 + r*32 + u, val);
      }
      if (t == TMAXX - 1){
        __syncthreads();
        if (tid == 0){
          float nn[5];
#pragma unroll
          for (int r = 0; r < 5; ++r) nn[r] = smF[56 + r] / (float)smI[80 + r];
          int used = 0;
#pragma unroll
          for (int r = 0; r < 5; ++r){
            int best = -1;
            for (int q2 = 0; q2 < 5; ++q2){
              if (used & (1 << q2)) continue;
              if (best < 0 || nn[q2] > nn[best]) best = q2;
            }
            used |= (1 << best);
            smI[88 + r] = best; smF[64 + r] = nn[best];
          }
        }
        __syncthreads();
        if (tid < 160){
          int r = tid >> 5, u = tid & 31;
          int src = smI[88 + r];
          out[tid] = (float)aload(seqA + nxt*160 + src*32 + u);
        }
        if (tid >= 160 && tid < 165) out[tid] = smF[64 + (tid - 160)];
      }
    });
  }
}

extern "C" void kernel_launch(void* const* d_in, const int* in_sizes, int n_in,
                              void* d_out, int out_size, void* d_ws, size_t ws_size,
                              hipStream_t stream)
{
  (void)in_sizes; (void)n_in; (void)out_size;
  hipMemsetAsync(d_ws, 0, 8192, stream);   // barrier counters/generations
  float* ws = (float*)d_ws;
  const bool packed = ws_size >= (size_t)WS_NEED;
  if (packed){
    k_pack<<<dim3(50, 512), dim3(256), 0, stream>>>((const float*)d_in[11], ws);
  }
  k_gi<<<dim3(256), dim3(256), 0, stream>>>(
      (const int*)d_in[0], (const float*)d_in[1],
      (const float*)d_in[2], (const float*)d_in[4], ws);
  k_enc<<<dim3(GENC), dim3(NT), 0, stream>>>(
      (const float*)d_in[3], (const float*)d_in[5], ws);
  k_ew<<<dim3(128), dim3(NT), 0, stream>>>(
      (const float*)d_in[10], ws);
  if (packed){
    k_dec<1><<<dim3(GW), dim3(NT), 0, stream>>>(
        (const float*)d_in[1],
        (const float*)d_in[6], (const float*)d_in[7],
        (const float*)d_in[8], (const float*)d_in[9],
        (const float*)d_in[10], (const float*)d_in[11],
        (float*)d_out, ws);
  } else {
    k_dec<0><<<dim3(GW), dim3(NT), 0, stream>>>(
        (const float*)d_in[1],
        (const float*)d_in[6], (const float*)d_in[7],
        (const float*)d_in[8], (const float*)d_in[9],
        (const float*)d_in[10], (const float*)d_in[11],
        (float*)d_out, ws);
  }
}

// Round 5
// 4004.085 us; speedup vs baseline: 1.6138x; 1.0812x over previous
//
#include <hip/hip_runtime.h>
#include <cstdint>
#include <cstddef>

// ---------------- problem constants ----------------
#define V_SZ 50257
#define H_SZ 512
#define S_SZ 128
#define NBEAM 5
#define TMAXX 32
#define TOK_SOS 1
#define TOK_EOS 2
#define NEGINF (-1e9f)

// ---------------- launch shape ----------------
#define GW 128            // decode workgroups (measured best; 256 regressed)
#define NT 512
#define GENC 16           // encoder WGs (Whh register-resident)
#define COLS_PER_WG 393   // ceil(V/GW)

// ---------------- packed-Wv (fp16 + fp16 residual) path ----------------
#define VPAD2 50304       // 128*393, mult of 64
#define WVP_OFF 1048576   // float offset of W16 [512][VPAD2] (byte 4 MiB)
#define WRT_OFF 13926400  // float offset of R16T [VPAD2][512] (byte 4MiB + 51.5MB)
#define WS_NEED (4194304ull + 2ull*(size_t)H_SZ*VPAD2*2ull)   // 107,216,896 B

// ---------------- barrier ints (start of ws; first 8 KiB memset to 0) ----------------
#define BI_LEAF(l)  ((l)*32)        // 8 leaf counters (16 WGs each)
#define BI_ROOT     544
#define BI_REL(l)   (1024 + (l)*32) // 8 per-leaf release generations
#define BI_ECNT     1792
#define BI_EREL     1824

// ---------------- float region: fb = (float*)ws + 2048 ----------------
#define OF_GI    0            // 128*1536
#define OF_ENC   196608       // 128*512
#define OF_EW    262144       // 128*512  enc_out @ Wc_bottom
#define OF_H2    327680       // [2][5][512] ping-pong decoder hidden
#define OF_AL    332800       // [5][128] attention logits
#define OF_OTOP  333440       // [5][512] h2 @ Wc_top (flat b*512+j)
#define OF_PV    336000       // [<=256][5][5]
#define OF_PM    342400       // [<=256][5]
#define OF_PS    343680       // [<=256][5]
#define OF_SC    344960       // [8]
#define OI_BASE  344968
#define I_TOK 6400
#define I_FIN 6408
#define I_LEN 6416
#define I_PAR 6424
#define I_SEQ 6432

template <typename T>
__device__ __forceinline__ T aload(const T* p){
  return __hip_atomic_load((T*)p, __ATOMIC_RELAXED, __HIP_MEMORY_SCOPE_AGENT);
}
template <typename T>
__device__ __forceinline__ void astore(T* p, T v){
  __hip_atomic_store(p, v, __ATOMIC_RELAXED, __HIP_MEMORY_SCOPE_AGENT);
}

__device__ __forceinline__ float wredsum(float a){
#pragma unroll
  for (int m = 32; m; m >>= 1) a += __shfl_xor(a, m, 64);
  return a;
}

// fence-free device barrier over GW WGs; last-arriving WG runs tail() before release.
template <typename F>
__device__ __forceinline__ void dbar(int* bi, int wid, F&& tail){
  __shared__ int s_last;
  int mygen = 0;
  __syncthreads();
  if (threadIdx.x == 0){
    int leaf = wid >> 4;
    mygen = aload(bi + BI_REL(leaf));
    __builtin_amdgcn_s_waitcnt(0);
    int lo = __hip_atomic_fetch_add(bi + BI_LEAF(leaf), 1, __ATOMIC_RELAXED, __HIP_MEMORY_SCOPE_AGENT);
    int last = 0;
    if (lo == 15){
      astore(bi + BI_LEAF(leaf), 0);
      __builtin_amdgcn_s_waitcnt(0);     // leaf reset at L3 before root arrive
      int ro = __hip_atomic_fetch_add(bi + BI_ROOT, 1, __ATOMIC_RELAXED, __HIP_MEMORY_SCOPE_AGENT);
      if (ro == (GW/16) - 1){
        astore(bi + BI_ROOT, 0);
        last = 1;
      }
    }
    if (!last){
      while (aload(bi + BI_REL(leaf)) == mygen) __builtin_amdgcn_s_sleep(4);
    }
    s_last = last;
  }
  __syncthreads();
  if (s_last){
    tail();
    __syncthreads();
    if (threadIdx.x == 0){
      __builtin_amdgcn_s_waitcnt(0);     // tail's sc1 stores + root reset at L3
#pragma unroll
      for (int l = 0; l < GW/16; ++l) astore(bi + BI_REL(l), mygen + 1);
    }
  }
  __syncthreads();
}

// ========== K0: pack Wv -> fp16 W16[512][VPAD2] + fp16 residual R16T[VPAD2][512] ==========
// LDS 64x64 tile transpose so both outputs are written coalesced.
__global__ __launch_bounds__(256)
void k_pack(const float* __restrict__ Wv, float* __restrict__ ws)
{
  __shared__ float tile[64][65];
  _Float16* wvh = (_Float16*)(ws + WVP_OFF);
  _Float16* wrt = (_Float16*)(ws + WRT_OFF);
  const int tid = threadIdx.x;
  const int vt = blockIdx.x * 64;    // v tile base
  const int ht = blockIdx.y * 64;    // h tile base
  const int lv = tid & 63, rg = tid >> 6;
  // load 64x64 (coalesced in v)
#pragma unroll
  for (int q = 0; q < 16; ++q){
    int hh = rg*16 + q;
    int v = vt + lv;
    float w = (v < V_SZ) ? Wv[(size_t)(ht+hh)*V_SZ + v] : 0.f;
    tile[hh][lv] = w;
  }
  __syncthreads();
  // write W16 [h][v] (coalesced in v)
#pragma unroll
  for (int q = 0; q < 16; ++q){
    int hh = rg*16 + q;
    wvh[(size_t)(ht+hh)*VPAD2 + vt + lv] = (_Float16)tile[hh][lv];
  }
  // write residual transposed [v][h] (coalesced in h); lane = h_local
#pragma unroll
  for (int q = 0; q < 16; ++q){
    int vv = rg*16 + q;
    float w = tile[lv][vv];           // (h_local=lv, v_local=vv); stride-65 -> conflict-free
    float w16 = (float)(_Float16)w;
    wrt[(size_t)(vt+vv)*H_SZ + ht + lv] = (_Float16)(w - w16);
  }
}

// ================= K1: gi = src_emb @ eWih^T + bih, plus beam-state init =================
__global__ __launch_bounds__(256)
void k_gi(const int* __restrict__ toks, const float* __restrict__ emb,
          const float* __restrict__ eWih, const float* __restrict__ ebih,
          float* __restrict__ ws)
{
  float* fb = ws + 2048;
  float* gi = fb + OF_GI;
  const int tid = threadIdx.x, wid = blockIdx.x, lane = tid & 63, wvi = tid >> 6;
  int Wg = wid*4 + wvi;                 // 0..1023
  for (int it = 0; it < 192; ++it){
    int idx = Wg*192 + it;              // covers 128*1536
    int s = idx / 1536, j = idx - s*1536;
    const float* er = emb + (size_t)toks[s]*H_SZ;
    const float* wr = eWih + (size_t)j*H_SZ;
    float a = 0.f;
#pragma unroll
    for (int u = 0; u < 8; ++u) a += er[u*64+lane]*wr[u*64+lane];
    a = wredsum(a);
    if (lane == 0) gi[idx] = a + ebih[j];
  }
  if (wid == 0){
    float* sc = fb + OF_SC;
    int* ib = (int*)(fb + OI_BASE);
    if (tid < NBEAM){
      sc[tid] = (tid==0) ? 0.f : NEGINF;
      ib[I_TOK+tid] = TOK_SOS; ib[I_FIN+tid] = 0; ib[I_LEN+tid] = 1; ib[I_PAR+tid] = 0;
    }
    for (int q = tid; q < 2*NBEAM*TMAXX; q += 256) ib[I_SEQ+q] = 0;
  }
}

// ================= K2: sequential encoder, 16 WGs, Whh in registers =================
__global__ __launch_bounds__(NT, 1)
void k_enc(const float* __restrict__ eWhh, const float* __restrict__ ebhh,
           float* __restrict__ ws)
{
  int* bi = (int*)ws;
  float* fb = ws + 2048;
  float* gi = fb + OF_GI;
  float* enc = fb + OF_ENC;
  const int tid = threadIdx.x, wid = blockIdx.x, lane = tid & 63, wvi = tid >> 6;
  const int i0 = wid*32;
  __shared__ float smF[96];

  float wreg[12][8];
#pragma unroll
  for (int dd = 0; dd < 12; ++dd){
    int d = wvi*12 + dd, g = d >> 5, il = d & 31;
    const float* wr = eWhh + (size_t)(g*512 + i0 + il)*H_SZ;
#pragma unroll
    for (int u = 0; u < 8; ++u) wreg[dd][u] = wr[u*64+lane];
  }
  float eb0 = 0.f, eb1 = 0.f, eb2 = 0.f;
  if (tid < 32){
    int i = i0 + tid;
    eb0 = ebhh[i]; eb1 = ebhh[512+i]; eb2 = ebhh[1024+i];
  }

  for (int s = 0; s < S_SZ; ++s){
    float hreg[8];
    if (s == 0){
#pragma unroll
      for (int u = 0; u < 8; ++u) hreg[u] = 0.f;
    } else {
      const float* hp = enc + (size_t)(s-1)*H_SZ;
#pragma unroll
      for (int u = 0; u < 8; ++u) hreg[u] = aload(hp + u*64 + lane);
    }
#pragma unroll
    for (int dd = 0; dd < 12; ++dd){
      float a = 0.f;
#pragma unroll
      for (int u = 0; u < 8; ++u) a += wreg[dd][u]*hreg[u];
      a = wredsum(a);
      if (lane == 0) smF[wvi*12 + dd] = a;
    }
    __syncthreads();
    if (tid < 32){
      int i = i0 + tid;
      float gr = smF[tid], gz = smF[32+tid], gn = smF[64+tid];
      float gir = gi[s*1536 + i], giz = gi[s*1536 + 512 + i], gin = gi[s*1536 + 1024 + i];
      float hprev = (s==0) ? 0.f : aload(enc + (s-1)*H_SZ + i);
      float r = 1.f/(1.f + expf(-(gir + gr + eb0)));
      float z = 1.f/(1.f + expf(-(giz + gz + eb1)));
      float n = tanhf(gin + r*(gn + eb2));
      astore(enc + s*H_SZ + i, (1.f - z)*n + z*hprev);
    }
    __syncthreads();
    if (tid == 0){
      int g = aload(bi + BI_EREL);
      __builtin_amdgcn_s_waitcnt(0);
      int lo = __hip_atomic_fetch_add(bi + BI_ECNT, 1, __ATOMIC_RELAXED, __HIP_MEMORY_SCOPE_AGENT);
      if (lo == GENC - 1){
        astore(bi + BI_ECNT, 0);
        __builtin_amdgcn_s_waitcnt(0);
        astore(bi + BI_EREL, g + 1);
      } else {
        while (aload(bi + BI_EREL) == g) __builtin_amdgcn_s_sleep(2);
      }
    }
    __syncthreads();
  }
}

// ================= K3: EW = enc_out @ Wc_bottom =================
__global__ __launch_bounds__(NT)
void k_ew(const float* __restrict__ Wc, float* __restrict__ ws)
{
  float* fb = ws + 2048;
  float* enc = fb + OF_ENC;
  float* EW  = fb + OF_EW;
  const int tid = threadIdx.x, wid = blockIdx.x;
  int jc = wid & 15, sb = wid >> 4;
  int jl = tid & 31, sl = (tid >> 5) & 15;
  int s = sb*16 + sl, j = jc*32 + jl;
  const float* er = enc + (size_t)s*H_SZ;
  const float* wc = Wc + (size_t)512*H_SZ;
  float a = 0.f;
  for (int k = 0; k < 512; ++k) a += er[k]*wc[(size_t)k*H_SZ + j];
  EW[s*H_SZ + j] = a;
}

// ====== K4: persistent decode; PACKED=1 -> fp16 GEMM screen + exact fp32 rescore ======
template<int PACKED>
__global__ __launch_bounds__(NT, 1)
void k_dec(const float* __restrict__ emb,
           const float* __restrict__ dWih, const float* __restrict__ dWhh,
           const float* __restrict__ dbih, const float* __restrict__ dbhh,
           const float* __restrict__ Wc,  const float* __restrict__ Wv,
           float* __restrict__ out, float* __restrict__ ws)
{
  const int wid = blockIdx.x, tid = threadIdx.x;
  const int lane = tid & 63, wvi = tid >> 6;
  int* bi = (int*)ws;
  float* fb = ws + 2048;
  float* enc  = fb + OF_ENC;
  float* EW   = fb + OF_EW;
  float* h2   = fb + OF_H2;
  float* al   = fb + OF_AL;
  float* otop = fb + OF_OTOP;
  float* pv   = fb + OF_PV;
  float* pm   = fb + OF_PM;
  float* ps   = fb + OF_PS;
  float* sc   = fb + OF_SC;
  int* ib   = (int*)(fb + OI_BASE);
  int* pidx = ib;
  int* tokA = ib + I_TOK;
  int* finA = ib + I_FIN;
  int* lenA = ib + I_LEN;
  int* parA = ib + I_PAR;
  int* seqA = ib + I_SEQ;   // [2][5][32]

  __shared__ float smF[512];
  __shared__ int   smI[256];
  __shared__ float s_buf[2560];   // stage A: h_prev rows; stage B: h2new; stage C: oo
  __shared__ float s_pp[648];     // softmax exp + sums

  const int i0 = wid*4;

  for (int t = 0; t < TMAXX; ++t){
    float* h2new = h2 + (t & 1)*2560;
    float* h2old = h2 + ((t & 1) ^ 1)*2560;

    // ---- Stage A: decoder GRU (4 hidden columns per WG) ----
    if (tid < NBEAM){ smI[tid] = aload(tokA + tid); smI[8 + tid] = t ? aload(parA + tid) : 0; }
    __syncthreads();
    if (t == 0){
      for (int q = tid; q < 2560; q += NT) s_buf[q] = enc[127*H_SZ + (q & 511)];
    } else {
      for (int q = tid; q < 2560; q += NT){
        int b = q >> 9;
        s_buf[q] = aload(h2old + smI[8 + b]*H_SZ + (q & 511));
      }
    }
    __syncthreads();
    {
      int mat = wvi >> 2;                       // waves 0-3: Wih(x); 4-7: Whh(h)
      float srg[5][8];
      if (mat == 0){
#pragma unroll
        for (int b = 0; b < NBEAM; ++b){
          const float* sp = emb + (size_t)smI[b]*H_SZ;
#pragma unroll
          for (int u = 0; u < 8; ++u) srg[b][u] = sp[u*64+lane];
        }
      } else {
#pragma unroll
        for (int b = 0; b < NBEAM; ++b)
#pragma unroll
          for (int u = 0; u < 8; ++u) srg[b][u] = s_buf[b*512 + u*64 + lane];
      }
      for (int rr = 0; rr < 3; ++rr){
        int R = wvi*3 + rr;                     // 0..23
        int rem = R - mat*12;
        int g = rem >> 2, il = rem & 3;
        const float* wr = ((mat==0) ? dWih : dWhh) + (size_t)(g*512 + i0 + il)*H_SZ;
        float wreg[8];
#pragma unroll
        for (int u = 0; u < 8; ++u) wreg[u] = wr[u*64+lane];
#pragma unroll
        for (int b = 0; b < NBEAM; ++b){
          float a = 0.f;
#pragma unroll
          for (int u = 0; u < 8; ++u) a += wreg[u]*srg[b][u];
          a = wredsum(a);
          if (lane == 0) smF[R*5 + b] = a;
        }
      }
      __syncthreads();
      if (tid < 20){
        int b = tid >> 2, il = tid & 3;
        int i = i0 + il;
        float ir  = smF[(0*12 + 0*4 + il)*5 + b] + dbih[i];
        float iz  = smF[(0*12 + 1*4 + il)*5 + b] + dbih[512+i];
        float inn = smF[(0*12 + 2*4 + il)*5 + b] + dbih[1024+i];
        float hr  = smF[(1*12 + 0*4 + il)*5 + b] + dbhh[i];
        float hz  = smF[(1*12 + 1*4 + il)*5 + b] + dbhh[512+i];
        float hn  = smF[(1*12 + 2*4 + il)*5 + b] + dbhh[1024+i];
        float r = 1.f/(1.f + expf(-(ir + hr)));
        float z = 1.f/(1.f + expf(-(iz + hz)));
        float n = tanhf(inn + r*hn);
        float hp = s_buf[b*512 + i];
        astore(h2new + b*H_SZ + i, (1.f - z)*n + z*hp);
      }
    }
    dbar(bi, wid, [&](){});

    // ---- Stage B: attention logits (s = wid) + otop = h2 @ Wc_top ----
    for (int q = tid; q < 2560; q += NT) s_buf[q] = aload(h2new + q);
    __syncthreads();
    if (wvi < NBEAM){
      const float* er = enc + (size_t)wid*H_SZ;
      float a = 0.f;
#pragma unroll
      for (int u = 0; u < 8; ++u) a += er[u*64+lane]*s_buf[wvi*512 + u*64 + lane];
      a = wredsum(a);
      if (lane == 0) astore(al + wvi*S_SZ + wid, a);
    }
    if (tid < 320){
      int q = tid % 20, ksl = tid / 20;
      int f = wid*20 + q;
      int b = f >> 9, j = f & 511;
      float a = 0.f;
#pragma unroll 8
      for (int u = 0; u < 32; ++u){
        int k = ksl*32 + u;
        a += s_buf[b*512 + k]*Wc[(size_t)k*H_SZ + j];
      }
      smF[q*16 + ksl] = a;
    }
    __syncthreads();
    if (tid < 20){
      float a = 0.f;
#pragma unroll
      for (int u = 0; u < 16; ++u) a += smF[tid*16 + u];
      astore(otop + wid*20 + tid, a);
    }
    dbar(bi, wid, [&](){});

    // ---- Stage C: local softmax + o, vocab GEMM, per-WG partials ----
    if (wvi < NBEAM){
      float a1 = aload(al + wvi*S_SZ + lane), a2 = aload(al + wvi*S_SZ + 64 + lane);
      float m = fmaxf(a1, a2);
#pragma unroll
      for (int mm = 32; mm; mm >>= 1) m = fmaxf(m, __shfl_xor(m, mm, 64));
      float e1 = expf(a1 - m), e2 = expf(a2 - m);
      s_pp[wvi*128 + lane] = e1; s_pp[wvi*128 + 64 + lane] = e2;
      float ssv = wredsum(e1 + e2);
      if (lane == 0) s_pp[640 + wvi] = ssv;
    }
    __syncthreads();
    {
      float acc[5] = {0.f,0.f,0.f,0.f,0.f};
      for (int s2 = 0; s2 < 128; ++s2){
        float e = EW[(size_t)s2*H_SZ + tid];
#pragma unroll
        for (int b = 0; b < NBEAM; ++b) acc[b] += e*s_pp[b*128 + s2];
      }
#pragma unroll
      for (int b = 0; b < NBEAM; ++b)
        s_buf[b*512 + tid] = tanhf(aload(otop + b*512 + tid) + acc[b]/s_pp[640 + b]);
    }
    __syncthreads();
    {
      int vbase = wid*COLS_PER_WG;
      int v = vbase + tid;
      bool act = (tid < COLS_PER_WG) && (v < V_SZ);
      int vc = act ? v : vbase;
      float a0=0.f,a1=0.f,a2=0.f,a3=0.f,a4=0.f;
      if constexpr (PACKED){
        const _Float16* wp = (const _Float16*)(ws + WVP_OFF) + vc;
        for (int hb = 0; hb < H_SZ; hb += 16){
          float wr[16];
#pragma unroll
          for (int u = 0; u < 16; ++u) wr[u] = (float)wp[(size_t)(hb+u)*VPAD2];
#pragma unroll
          for (int u = 0; u < 16; ++u){
            float w = wr[u];
            a0 += w*s_buf[hb+u];
            a1 += w*s_buf[512+hb+u];
            a2 += w*s_buf[1024+hb+u];
            a3 += w*s_buf[1536+hb+u];
            a4 += w*s_buf[2048+hb+u];
          }
        }
      } else {
        const float* wp = Wv + vc;
        for (int hb = 0; hb < H_SZ; hb += 16){
          float wr[16];
#pragma unroll
          for (int u = 0; u < 16; ++u) wr[u] = wp[(size_t)(hb+u)*V_SZ];
#pragma unroll
          for (int u = 0; u < 16; ++u){
            float w = wr[u];
            a0 += w*s_buf[hb+u];
            a1 += w*s_buf[512+hb+u];
            a2 += w*s_buf[1024+hb+u];
            a3 += w*s_buf[1536+hb+u];
            a4 += w*s_buf[2048+hb+u];
          }
        }
      }
      if (!act){ a0=a1=a2=a3=a4=-3e38f; }
      int myv = act ? v : 0x7FFFFFFF;
      float accs[5] = {a0,a1,a2,a3,a4};
      // per-wave top-5 + softmax partials (fp16-based when PACKED; fine for LSE)
#pragma unroll
      for (int b = 0; b < NBEAM; ++b){
        float x = accs[b];
        float m = x;
#pragma unroll
        for (int mm = 32; mm; mm >>= 1) m = fmaxf(m, __shfl_xor(m, mm, 64));
        float e = expf(x - m);
        float ssum = wredsum(e);
        float bv = x; int bc = myv;
        float w5[5]; int i5[5];
#pragma unroll
        for (int r = 0; r < 5; ++r){
          float cv2 = bv; int ci2 = bc;
#pragma unroll
          for (int mm = 32; mm; mm >>= 1){
            float ov = __shfl_xor(cv2, mm, 64); int oi = __shfl_xor(ci2, mm, 64);
            bool take = (ov > cv2) || (ov == cv2 && oi < ci2);
            cv2 = take ? ov : cv2; ci2 = take ? oi : ci2;
          }
          w5[r] = cv2; i5[r] = ci2;
          if (bc == ci2) bv = -3e38f;
        }
        if (lane == 0){
#pragma unroll
          for (int r = 0; r < 5; ++r){ smF[(wvi*5+b)*5+r] = w5[r]; smI[(wvi*5+b)*5+r] = i5[r]; }
          smF[300 + wvi*5 + b] = m;
          smF[360 + wvi*5 + b] = ssum;
        }
      }
      __syncthreads();
      if (tid < NBEAM){
        float M = -3.4e38f, Sv = 0.f;
#pragma unroll
        for (int w8 = 0; w8 < 8; ++w8){
          float m2 = smF[300 + w8*5 + tid], s2 = smF[360 + w8*5 + tid];
          if (m2 > M){ Sv = Sv*expf(M - m2) + s2; M = m2; }
          else       { Sv = Sv + s2*expf(m2 - M); }
        }
        astore(pm + wid*5 + tid, M); astore(ps + wid*5 + tid, Sv);
      }

      if constexpr (PACKED){
        // ---- merge 40 fp16 wave-winners -> per-beam top-8 (into smF[400+], smI[200+]) ----
        if (wvi < NBEAM){
          int b = wvi;
          float cval; int cidx;
          if (lane < 40){ cval = smF[((lane/5)*5 + b)*5 + (lane%5)]; cidx = smI[((lane/5)*5 + b)*5 + (lane%5)]; }
          else { cval = -3e38f; cidx = 0x7FFFFFFF; }
          float bv = cval; int bc = cidx;
#pragma unroll
          for (int r = 0; r < 8; ++r){
            float cv2 = bv; int ci2 = bc;
#pragma unroll
            for (int mm = 32; mm; mm >>= 1){
              float ov = __shfl_xor(cv2, mm, 64); int oi = __shfl_xor(ci2, mm, 64);
              bool take = (ov > cv2) || (ov == cv2 && oi < ci2);
              cv2 = take ? ov : cv2; ci2 = take ? oi : ci2;
            }
            if (lane == 0){ smF[400 + b*8 + r] = cv2; smI[200 + b*8 + r] = ci2; }
            if (bc == ci2) bv = -3e38f;
          }
        }
        __syncthreads();
        // ---- exact rescore: 40 (beam,cand) pairs, 5 per wave; Δ = dot(R16T[v], o_b) ----
        {
          const _Float16* wrt = (const _Float16*)(ws + WRT_OFF);
          for (int pp = 0; pp < 5; ++pp){
            int p = wvi*5 + pp;                 // 0..39
            int b = p >> 3, k = p & 7;
            int idx = smI[200 + b*8 + k];
            bool valid = (idx != 0x7FFFFFFF);
            int ic = valid ? idx : 0;
            const _Float16* rr = wrt + (size_t)ic*H_SZ + lane*8;
            const float* ob = s_buf + b*512 + lane*8;
            float d = 0.f;
#pragma unroll
            for (int u = 0; u < 8; ++u) d += (float)rr[u]*ob[u];
            d = wredsum(d);
            if (lane == 0 && valid) smF[400 + b*8 + k] += d;
          }
        }
        __syncthreads();
        // ---- exact top-5 per beam from corrected 8, write pv/pidx ----
        if (tid < NBEAM){
          float v8[8]; int i8[8];
#pragma unroll
          for (int k = 0; k < 8; ++k){ v8[k] = smF[400 + tid*8 + k]; i8[k] = smI[200 + tid*8 + k]; }
#pragma unroll
          for (int a = 1; a < 8; ++a){
            float vv = v8[a]; int ii = i8[a];
            int p = a;
            while (p > 0 && ((v8[p-1] < vv) || (v8[p-1] == vv && i8[p-1] > ii))){
              v8[p] = v8[p-1]; i8[p] = i8[p-1]; --p;
            }
            v8[p] = vv; i8[p] = ii;
          }
#pragma unroll
          for (int r = 0; r < 5; ++r){
            astore(pv + (wid*5+tid)*5+r, v8[r]); astore(pidx + (wid*5+tid)*5+r, i8[r]);
          }
        }
      } else {
        // exact path: direct per-beam top-5 from 40 wave winners (round-0 behavior)
        if (wvi < NBEAM){
          int b = wvi;
          float cval; int cidx;
          if (lane < 40){ cval = smF[((lane/5)*5 + b)*5 + (lane%5)]; cidx = smI[((lane/5)*5 + b)*5 + (lane%5)]; }
          else { cval = -3e38f; cidx = 0x7FFFFFFF; }
          float bv = cval; int bc = cidx;
#pragma unroll
          for (int r = 0; r < 5; ++r){
            float cv2 = bv; int ci2 = bc;
#pragma unroll
            for (int mm = 32; mm; mm >>= 1){
              float ov = __shfl_xor(cv2, mm, 64); int oi = __shfl_xor(ci2, mm, 64);
              bool take = (ov > cv2) || (ov == cv2 && oi < ci2);
              cv2 = take ? ov : cv2; ci2 = take ? oi : ci2;
            }
            if (lane == 0){ astore(pv + (wid*5+b)*5+r, cv2); astore(pidx + (wid*5+b)*5+r, ci2); }
            if (bc == ci2) bv = -3e38f;
          }
        }
      }
    }

    dbar(bi, wid, [&](){
      // ======== Stage D (barrier tail, one WG): merge 2x64 WG groups ========
      int b5 = wvi;
      if (b5 < NBEAM){
        float m1 = aload(pm + lane*5 + b5), s1 = aload(ps + lane*5 + b5);
        float m2 = aload(pm + (64+lane)*5 + b5), s2 = aload(ps + (64+lane)*5 + b5);
        float M, Sv;
        if (m1 >= m2){ M = m1; Sv = s1 + s2*expf(m2 - m1); }
        else         { M = m2; Sv = s2 + s1*expf(m1 - m2); }
#pragma unroll
        for (int mm = 32; mm; mm >>= 1){
          float om = __shfl_xor(M, mm, 64), os = __shfl_xor(Sv, mm, 64);
          if (om > M){ Sv = Sv*expf(M - om) + os; M = om; }
          else       { Sv = Sv + os*expf(om - M); }
        }
        if (lane == 0){ smF[8 + b5] = M; smF[80 + b5] = logf(Sv); }
        // prefetch BOTH groups' top-5 lists up-front (independent loads, one L3 latency)
        float lv[5]; int li[5];
        float nv5[5]; int ni5[5];
#pragma unroll
        for (int r = 0; r < 5; ++r){
          lv[r]  = aload(pv + (lane*5 + b5)*5 + r);      li[r]  = aload(pidx + (lane*5 + b5)*5 + r);
          nv5[r] = aload(pv + ((64+lane)*5 + b5)*5 + r); ni5[r] = aload(pidx + ((64+lane)*5 + b5)*5 + r);
        }
        for (int r = 0; r < 5; ++r){
          bool ins = (nv5[r] > lv[4]) || (nv5[r] == lv[4] && ni5[r] < li[4]);
          if (!ins) break;
          lv[4] = nv5[r]; li[4] = ni5[r];
#pragma unroll
          for (int p = 4; p > 0; --p){
            bool sw = (lv[p] > lv[p-1]) || (lv[p] == lv[p-1] && li[p] < li[p-1]);
            if (sw){ float tv = lv[p]; lv[p] = lv[p-1]; lv[p-1] = tv;
                     int ti = li[p]; li[p] = li[p-1]; li[p-1] = ti; }
          }
        }
        float cv = lv[0]; int ci = li[0];
#pragma unroll
        for (int r = 0; r < 5; ++r){
          float xv = cv; int xi = ci;
#pragma unroll
          for (int mm = 32; mm; mm >>= 1){
            float ov = __shfl_xor(xv, mm, 64); int oi = __shfl_xor(xi, mm, 64);
            bool take = (ov > xv) || (ov == xv && oi < xi);
            xv = take ? ov : xv; xi = take ? oi : xi;
          }
          if (lane == 0){ smF[16 + b5*5 + r] = xv; smI[16 + b5*5 + r] = xi; }
          if (ci == xi){
            lv[0]=lv[1]; li[0]=li[1]; lv[1]=lv[2]; li[1]=li[2];
            lv[2]=lv[3]; li[2]=li[3]; lv[3]=lv[4]; li[3]=li[4];
            lv[4] = -3e38f; li[4] = 0x7FFFFFFF;
            cv = lv[0]; ci = li[0];
          }
        }
      }
      __syncthreads();
      if (wvi == 0){
        float cval = -3e38f; int cflat = 0x7FFFFFFF;
        int b = lane/5, k = lane - b*5;
        if (lane < 25){
          if (aload(finA + b)){
            if (k == 0){ cval = aload(sc + b) + 0.0f; cflat = b*V_SZ + TOK_EOS; }
          } else {
            cval = ((smF[16 + b*5 + k] - smF[8 + b]) - smF[80 + b]) + aload(sc + b);
            cflat = b*V_SZ + smI[16 + b*5 + k];
          }
        }
        float bv = cval; int bc = cflat;
#pragma unroll
        for (int r = 0; r < 5; ++r){
          float xv = bv; int xi = bc;
#pragma unroll
          for (int mm = 32; mm; mm >>= 1){
            float ov = __shfl_xor(xv, mm, 64); int oi = __shfl_xor(xi, mm, 64);
            bool take = (ov > xv) || (ov == xv && oi < xi);
            xv = take ? ov : xv; xi = take ? oi : xi;
          }
          if (lane == 0){ smF[48 + r] = xv; smI[48 + r] = xi; }
          if (bc == xi) bv = -3e38f;
        }
        if (lane < NBEAM){
          int r = lane;
          float nscore = smF[48 + r]; int nfl = smI[48 + r];
          int par = nfl / V_SZ; int tok = nfl - par*V_SZ;
          int ofin = aload(finA + par); int olen = aload(lenA + par);  // reads before writes (wave-lockstep)
          int nf = (ofin || tok == TOK_EOS) ? 1 : 0;
          int nl = olen + (ofin ? 0 : 1);
          astore(sc + r, nscore); astore(tokA + r, tok); astore(finA + r, nf);
          astore(lenA + r, nl); astore(parA + r, par);
          smI[56 + r] = par; smI[64 + r] = tok; smI[72 + r] = ofin; smI[80 + r] = nl;
          smF[56 + r] = nscore;
        }
      }
      __syncthreads();
      int cur = t & 1, nxt = 1 - cur;
      if (tid < 160){
        int r = tid >> 5, u = tid & 31;
        int par = smI[56 + r];
        int val = aload(seqA + cur*160 + par*32 + u);
        if (u == t) val = smI[72 + r] ? 0 : smI[64 + r];
        astore(seqA + nxt*160 + r*32 + u, val);
      }
      if (t == TMAXX - 1){
        __syncthreads();
        if (tid == 0){
          float nn[5];
#pragma unroll
          for (int r = 0; r < 5; ++r) nn[r] = smF[56 + r] / (float)smI[80 + r];
          int used = 0;
#pragma unroll
          for (int r = 0; r < 5; ++r){
            int best = -1;
            for (int q2 = 0; q2 < 5; ++q2){
              if (used & (1 << q2)) continue;
              if (best < 0 || nn[q2] > nn[best]) best = q2;
            }
            used |= (1 << best);
            smI[88 + r] = best; smF[64 + r] = nn[best];
          }
        }
        __syncthreads();
        if (tid < 160){
          int r = tid >> 5, u = tid & 31;
          int src = smI[88 + r];
          out[tid] = (float)aload(seqA + nxt*160 + src*32 + u);
        }
        if (tid >= 160 && tid < 165) out[tid] = smF[64 + (tid - 160)];
      }
    });
  }
}

extern "C" void kernel_launch(void* const* d_in, const int* in_sizes, int n_in,
                              void* d_out, int out_size, void* d_ws, size_t ws_size,
                              hipStream_t stream)
{
  (void)in_sizes; (void)n_in; (void)out_size;
  hipMemsetAsync(d_ws, 0, 8192, stream);   // barrier counters/generations
  float* ws = (float*)d_ws;
  const bool packed = ws_size >= (size_t)WS_NEED;
  if (packed){
    k_pack<<<dim3(VPAD2/64, 8), dim3(256), 0, stream>>>((const float*)d_in[11], ws);
  }
  k_gi<<<dim3(256), dim3(256), 0, stream>>>(
      (const int*)d_in[0], (const float*)d_in[1],
      (const float*)d_in[2], (const float*)d_in[4], ws);
  k_enc<<<dim3(GENC), dim3(NT), 0, stream>>>(
      (const float*)d_in[3], (const float*)d_in[5], ws);
  k_ew<<<dim3(128), dim3(NT), 0, stream>>>(
      (const float*)d_in[10], ws);
  if (packed){
    k_dec<1><<<dim3(GW), dim3(NT), 0, stream>>>(
        (const float*)d_in[1],
        (const float*)d_in[6], (const float*)d_in[7],
        (const float*)d_in[8], (const float*)d_in[9],
        (const float*)d_in[10], (const float*)d_in[11],
        (float*)d_out, ws);
  } else {
    k_dec<0><<<dim3(GW), dim3(NT), 0, stream>>>(
        (const float*)d_in[1],
        (const float*)d_in[6], (const float*)d_in[7],
        (const float*)d_in[8], (const float*)d_in[9],
        (const float*)d_in[10], (const float*)d_in[11],
        (float*)d_out, ws);
  }
}